// Round 6
// baseline (1851.958 us; speedup 1.0000x reference)
//
#include <hip/hip_runtime.h>
#include <hip/hip_bf16.h>
#include <math.h>

typedef __hip_bfloat16 bf16;
typedef __attribute__((ext_vector_type(8))) short short8;
typedef __attribute__((ext_vector_type(4))) short s16x4;
typedef __attribute__((ext_vector_type(4))) float f32x4;

#define D_    512
#define H_    4
#define DH_   128
#define L_    4
#define FF_   512
#define B_    64
#define NH_   6
#define S_    256
#define T_    64
#define IMG_  2048
#define NTMAIN (B_ * S_)              // 16384
#define NTHIST (B_ * NH_ * T_)        // 24576
#define NTALL  (NTMAIN + NTHIST)      // 40960
#define QCHUNK ((size_t)NTHIST * D_)  // element stride between q,k,v buffers (split path)
#define QALL   ((size_t)NTALL * D_)   // element stride between q,k,v buffers (merged path)

// async global->LDS, 16B per lane, LDS dest = wave-uniform base + lane*16
#define GLOAD_LDS(gp, lp) __builtin_amdgcn_global_load_lds( \
    (const __attribute__((address_space(1))) void*)(gp),    \
    (__attribute__((address_space(3))) void*)(lp), 16, 0, 0)

__device__ __forceinline__ float toF(bf16 v)  { return __bfloat162float(v); }
__device__ __forceinline__ float toF(float v) { return v; }
__device__ __forceinline__ void storeF(bf16* p, float v)  { *p = __float2bfloat16(v); }
__device__ __forceinline__ void storeF(float* p, float v) { *p = v; }

// round-to-nearest-even f32 -> bf16 bits
__device__ __forceinline__ unsigned short f2b(float f) {
    unsigned u = __float_as_uint(f);
    unsigned r = (u + 0x7fffu + ((u >> 16) & 1u)) >> 16;
    return (unsigned short)r;
}
// bf16 bits -> f32 (exact)
__device__ __forceinline__ float b2f(short b) {
    return __uint_as_float(((unsigned)(unsigned short)b) << 16);
}

// ---- weight transpose + cast: src[R][C] fp32 -> dst[C][R] bf16, z = layer ----
__global__ void transpose_cast(const float* __restrict__ src, bf16* __restrict__ dst,
                               int R, int Cc, size_t dstride) {
    __shared__ float t[32][33];
    src += (size_t)blockIdx.z * R * Cc;
    dst += (size_t)blockIdx.z * dstride;
    int c0 = blockIdx.x * 32, r0 = blockIdx.y * 32;
    int tx = threadIdx.x & 31, ty = threadIdx.x >> 5;  // 256 thr: ty 0..7
    for (int i = ty; i < 32; i += 8) t[i][tx] = src[(size_t)(r0 + i) * Cc + c0 + tx];
    __syncthreads();
    for (int i = ty; i < 32; i += 8)
        dst[(size_t)(c0 + i) * R + r0 + tx] = __float2bfloat16(t[tx][i]);
}

// ---- flat f32 -> bf16 cast ----
__global__ void cast_bf16(const float* __restrict__ src, bf16* __restrict__ dst, int n) {
    int i = blockIdx.x * blockDim.x + threadIdx.x;
    if (i < n) dst[i] = __float2bfloat16(src[i]);
}

// ---- gather qkv bias: o[l][0:512]=bq[l], [512:1024]=bk[l], [1024:1536]=bv[l] ----
__global__ void gather_qkv_bias(const float* __restrict__ bq, const float* __restrict__ bk,
                                const float* __restrict__ bv, float* __restrict__ o) {
    int idx = blockIdx.x * blockDim.x + threadIdx.x;  // L_*1536 = 6144
    if (idx >= L_ * 1536) return;
    int l = idx / 1536, j = idx - l * 1536;
    int which = j >> 9, rem = j & 511;
    const float* s = (which == 0) ? bq : (which == 1) ? bk : bv;
    o[idx] = s[l * 512 + rem];
}

// ---- positional-encoding table: pe[t][d], t < S_, d < D_ ----
__global__ void pe_kernel(float* __restrict__ pe) {
    int idx = blockIdx.x * blockDim.x + threadIdx.x;
    if (idx >= S_ * D_) return;
    int d = idx & (D_ - 1), t = idx >> 9;
    int i = d >> 1;
    float dv  = expf(-(float)(2 * i) * (9.210340371976184f / 512.0f));
    float ang = (float)t * dv;
    pe[idx] = (d & 1) ? cosf(ang) : sinf(ang);
}

// ---- embedding + PE-table add: 4 elems/thread, vectorized ----
__global__ void embed_kernel(const int* __restrict__ tokens,
                             const float* __restrict__ emb,
                             const float* __restrict__ pe,
                             bf16* __restrict__ x16,
                             int Tt, int total4) {
    int idx = blockIdx.x * blockDim.x + threadIdx.x;
    if (idx >= total4) return;
    int d4  = (idx & 127) * 4;      // D_/4 = 128 groups per row
    int row = idx >> 7;
    int t   = row & (Tt - 1);       // Tt is a power of two (256 or 64)
    int tok = tokens[row];
    f32x4 e = *(const f32x4*)&emb[(size_t)tok * D_ + d4];
    f32x4 p = *(const f32x4*)&pe[(size_t)t * D_ + d4];
    s16x4 o;
#pragma unroll
    for (int j = 0; j < 4; ++j) o[j] = (short)f2b(e[j] + p[j]);
    *(s16x4*)&x16[(size_t)row * D_ + d4] = o;
}

// ---- MFMA bf16 GEMM, 128x128 tile, 4 waves, proven core (K=512 unrolled) ----
// lt >= 0 : qkv scatter for a single encoder (row block size 1<<lt)
// lt == -1: plain row-major C (optional addC/relu)
// lt == -2: merged qkv scatter: rows < NTMAIN -> main (lt=8), else hist (lt=6),
//           q/k/v chunks strided by QALL, hist sub-offset NTMAIN*D_.
template <typename CT>
__global__ __launch_bounds__(256) void gemm_mfma(
    const bf16* __restrict__ A, const bf16* __restrict__ Bt,
    const float* __restrict__ bias, CT* __restrict__ C,
    int M, int N, int K, int lt, int relu, int addC, int vt) {
    __shared__ short As[128 * 64];
    __shared__ short Bs[128 * 64];
    int tid  = threadIdx.x;
    int wave = tid >> 6, lane = tid & 63, lr = lane & 15, quad = lane >> 4;
    int wr = (wave >> 1) * 64, wc = (wave & 1) * 64;
    int bx = blockIdx.x, by = blockIdx.y;
    if ((gridDim.y & 7) == 0) {
        int id = by * gridDim.x + bx;
        int xcd = id & 7, slot = id >> 3;
        by = xcd + 8 * (slot / gridDim.x);
        bx = slot % gridDim.x;
    }
    int row0 = by * 128, col0 = bx * 128;
    int srow   = lane >> 3;                    // 0..7 within 8-row segment
    int gchunk = (lane & 7) ^ srow;            // XOR-swizzled source chunk
    f32x4 acc[4][4];
    f32x4 zz = {0.f, 0.f, 0.f, 0.f};
#pragma unroll
    for (int mi = 0; mi < 4; ++mi)
#pragma unroll
        for (int ni = 0; ni < 4; ++ni) acc[mi][ni] = zz;

    int lr7 = lr & 7;
    auto ktile = [&](int kt) {
#pragma unroll
        for (int sseg = 0; sseg < 4; ++sseg) {
            int s = wave + sseg * 4;           // segment 0..15
            int rloc = s * 8 + srow;
            const bf16* gA = &A[(size_t)(row0 + rloc) * K + kt + gchunk * 8];
            const bf16* gB = &Bt[(size_t)(col0 + rloc) * K + kt + gchunk * 8];
            GLOAD_LDS(gA, &As[s * 512]);
            GLOAD_LDS(gB, &Bs[s * 512]);
        }
        __syncthreads();   // drains vmcnt (async LDS writes) + barrier
#pragma unroll
        for (int ks = 0; ks < 2; ++ks) {
            int cp = (((ks * 4) + quad) ^ lr7) * 8;
            short8 af[4], bf4[4];
#pragma unroll
            for (int mi = 0; mi < 4; ++mi)
                af[mi] = *(const short8*)&As[(wr + mi * 16 + lr) * 64 + cp];
#pragma unroll
            for (int ni = 0; ni < 4; ++ni)
                bf4[ni] = *(const short8*)&Bs[(wc + ni * 16 + lr) * 64 + cp];
#pragma unroll
            for (int mi = 0; mi < 4; ++mi)
#pragma unroll
                for (int ni = 0; ni < 4; ++ni)
                    acc[mi][ni] = __builtin_amdgcn_mfma_f32_16x16x32_bf16(
                        af[mi], bf4[ni], acc[mi][ni], 0, 0, 0);
        }
        __syncthreads();   // protect LDS reuse before next iteration's async writes
    };
    if (K == 512) {
        // constant trip count: staging addresses fold to base + imm offsets
#pragma unroll
        for (int t8 = 0; t8 < 8; ++t8) ktile(t8 * 64);
    } else {
        for (int kt = 0; kt < K; kt += 64) ktile(kt);
    }

#pragma unroll
    for (int ni = 0; ni < 4; ++ni) {
        int gc = col0 + wc + ni * 16 + lr;
        float bi = bias[gc];
#pragma unroll
        for (int mi = 0; mi < 4; ++mi) {
            int gr0 = row0 + wr + mi * 16 + quad * 4;
            f32x4 vv = acc[mi][ni];
            if (lt != -1) {
                // qkv scatter path (bf16 C only in practice)
                int ltl = (lt == -2) ? ((gr0 < NTMAIN) ? 8 : 6) : lt;
                size_t qstr = (lt == -2) ? QALL : QCHUNK;
                size_t sub  = (lt == -2 && gr0 >= NTMAIN) ? (size_t)NTMAIN * D_ : 0;
                int rb      = (lt == -2 && gr0 >= NTMAIN) ? gr0 - NTMAIN : gr0;
                int which = gc >> 9;              // 0=q,1=k,2=v (fused qkv)
                int h2 = (gc >> 7) & 3, dh = gc & 127;
                size_t base = (size_t)which * qstr + sub;
                int Tm = (1 << ltl) - 1;
                if (which == 2) {
                    // v layout: consecutive qi contiguous -> one 8B store
                    int mq = rb >> ltl, qi0 = rb & Tm;   // rb aligned 4
                    size_t oi0 = base + ((((size_t)(mq * H_ + h2)) * DH_ + dh) << ltl) + qi0;
                    s16x4 o;
#pragma unroll
                    for (int rr = 0; rr < 4; ++rr) o[rr] = (short)f2b(vv[rr] + bi);
                    *(s16x4*)((bf16*)C + oi0) = o;
                } else {
#pragma unroll
                    for (int rr = 0; rr < 4; ++rr) {
                        int r = rb + rr;
                        int mq = r >> ltl, qi = r & Tm;
                        size_t oi = base + ((((size_t)(mq * H_ + h2)) << ltl) + qi) * DH_ + dh;
                        storeF(&C[oi], vv[rr] + bi);
                    }
                }
            } else {
#pragma unroll
                for (int rr = 0; rr < 4; ++rr) {
                    int r = gr0 + rr;
                    float val = vv[rr] + bi;
                    size_t oi = (size_t)r * N + gc;
                    if (addC) val += toF(C[oi]);
                    if (relu) val = fmaxf(val, 0.f);
                    storeF(&C[oi], val);
                }
            }
        }
    }
}

// ---- MFMA flash attention: shared body, two entry points ----
struct AttnSmem {
    short Ks[64][136];
    short Vs[128][72];
    short Ps[4][16][72];
};

__device__ __forceinline__ void attn_body(
    AttnSmem& sm,
    const bf16* __restrict__ q, const bf16* __restrict__ k, const bf16* __restrict__ vt,
    bf16* __restrict__ ctx, const int* __restrict__ lens, int Tt, int nqt, int bx) {
    int qt = bx % nqt, mh = bx / nqt;
    int m = mh >> 2, h = mh & 3;
    int tid  = threadIdx.x;
    int wave = tid >> 6, lane = tid & 63, lr = lane & 15, quad = lane >> 4;
    int q0 = qt * 64;
    int kvalid = Tt;
    if (lens) { int l0 = lens[m]; kvalid = l0 < 1 ? 1 : l0; }

    short8 aq[4];
    const bf16* qrow = q + ((size_t)mh * Tt + q0 + wave * 16 + lr) * DH_;
#pragma unroll
    for (int ks2 = 0; ks2 < 4; ++ks2)
        aq[ks2] = *(const short8*)&qrow[ks2 * 32 + quad * 8];

    float mrow[4], lrow[4];
#pragma unroll
    for (int r = 0; r < 4; ++r) { mrow[r] = -INFINITY; lrow[r] = 0.f; }
    f32x4 acco[8];
    f32x4 zz = {0.f, 0.f, 0.f, 0.f};
#pragma unroll
    for (int n = 0; n < 8; ++n) acco[n] = zz;

    int nkt = Tt >> 6;
    for (int kt = 0; kt < nkt; ++kt) {
        int kb = kt * 64;
        __syncthreads();
#pragma unroll
        for (int ee = 0; ee < 4; ++ee) {
            int e = tid + ee * 256;
            int r = e >> 4, c = (e & 15) * 8;
            *(short8*)&sm.Ks[r][c] = *(const short8*)&k[((size_t)mh * Tt + kb + r) * DH_ + c];
        }
#pragma unroll
        for (int ee = 0; ee < 4; ++ee) {
            int e = tid + ee * 256;
            int r = e >> 3, c = (e & 7) * 8;
            *(short8*)&sm.Vs[r][c] = *(const short8*)&vt[((size_t)mh * DH_ + r) * Tt + kb + c];
        }
        __syncthreads();
        f32x4 s[4];
#pragma unroll
        for (int ni = 0; ni < 4; ++ni) s[ni] = zz;
#pragma unroll
        for (int ni = 0; ni < 4; ++ni)
#pragma unroll
            for (int ks2 = 0; ks2 < 4; ++ks2) {
                short8 kf = *(const short8*)&sm.Ks[ni * 16 + lr][ks2 * 32 + quad * 8];
                s[ni] = __builtin_amdgcn_mfma_f32_16x16x32_bf16(aq[ks2], kf, s[ni], 0, 0, 0);
            }
        float mx[4] = {-INFINITY, -INFINITY, -INFINITY, -INFINITY};
#pragma unroll
        for (int ni = 0; ni < 4; ++ni) {
            bool ok = (kb + ni * 16 + lr) < kvalid;
#pragma unroll
            for (int reg = 0; reg < 4; ++reg) {
                float v = s[ni][reg] * 0.08838834764831845f;
                v = ok ? v : -INFINITY;
                s[ni][reg] = v;
                mx[reg] = fmaxf(mx[reg], v);
            }
        }
#pragma unroll
        for (int d2 = 1; d2 < 16; d2 <<= 1)
#pragma unroll
            for (int reg = 0; reg < 4; ++reg)
                mx[reg] = fmaxf(mx[reg], __shfl_xor(mx[reg], d2));
        float alpha[4];
#pragma unroll
        for (int reg = 0; reg < 4; ++reg) {
            float mn = fmaxf(mrow[reg], mx[reg]);
            alpha[reg] = __expf(mrow[reg] - mn);
            mrow[reg] = mn;
        }
        float rs[4] = {0.f, 0.f, 0.f, 0.f};
#pragma unroll
        for (int ni = 0; ni < 4; ++ni)
#pragma unroll
            for (int reg = 0; reg < 4; ++reg) {
                float p = __expf(s[ni][reg] - mrow[reg]);
                s[ni][reg] = p;
                rs[reg] += p;
            }
#pragma unroll
        for (int d2 = 1; d2 < 16; d2 <<= 1)
#pragma unroll
            for (int reg = 0; reg < 4; ++reg)
                rs[reg] += __shfl_xor(rs[reg], d2);
#pragma unroll
        for (int reg = 0; reg < 4; ++reg)
            lrow[reg] = lrow[reg] * alpha[reg] + rs[reg];
#pragma unroll
        for (int ni = 0; ni < 4; ++ni)
#pragma unroll
            for (int reg = 0; reg < 4; ++reg)
                sm.Ps[wave][quad * 4 + reg][ni * 16 + lr] = (short)f2b(s[ni][reg]);
#pragma unroll
        for (int n = 0; n < 8; ++n)
#pragma unroll
            for (int reg = 0; reg < 4; ++reg) acco[n][reg] *= alpha[reg];
#pragma unroll
        for (int ks2 = 0; ks2 < 2; ++ks2) {
            short8 pf = *(const short8*)&sm.Ps[wave][lr][ks2 * 32 + quad * 8];
#pragma unroll
            for (int n = 0; n < 8; ++n) {
                short8 vf = *(const short8*)&sm.Vs[n * 16 + lr][ks2 * 32 + quad * 8];
                acco[n] = __builtin_amdgcn_mfma_f32_16x16x32_bf16(pf, vf, acco[n], 0, 0, 0);
            }
        }
    }
    float linv[4];
#pragma unroll
    for (int reg = 0; reg < 4; ++reg) linv[reg] = 1.f / lrow[reg];
#pragma unroll
    for (int n = 0; n < 8; ++n)
#pragma unroll
        for (int reg = 0; reg < 4; ++reg) {
            int qq = q0 + wave * 16 + quad * 4 + reg;
            ctx[((size_t)m * Tt + qq) * D_ + h * DH_ + n * 16 + lr] =
                __float2bfloat16(acco[n][reg] * linv[reg]);
        }
}

// standalone (split/fallback path)
__global__ __launch_bounds__(256) void fused_attn(
    const bf16* __restrict__ q, const bf16* __restrict__ k, const bf16* __restrict__ vt,
    bf16* __restrict__ ctx, const int* __restrict__ lens, int Tt, int nqt) {
    __shared__ AttnSmem sm;
    attn_body(sm, q, k, vt, ctx, lens, Tt, nqt, blockIdx.x);
}

// merged main+hist attention: blocks [0,1024) main, [1024,2560) hist
__global__ __launch_bounds__(256) void fused_attn2(
    const bf16* __restrict__ qkv, bf16* __restrict__ ctxb, const int* __restrict__ lens) {
    __shared__ AttnSmem sm;
    int bx = blockIdx.x;
    const bf16* q  = qkv;
    const bf16* k  = qkv + QALL;
    const bf16* vt = qkv + 2 * QALL;
    const int NMAINB = B_ * H_ * (S_ / 64);   // 1024
    if (bx < NMAINB) {
        attn_body(sm, q, k, vt, ctxb, nullptr, S_, S_ / 64, bx);
    } else {
        size_t off = (size_t)NTMAIN * D_;
        attn_body(sm, q + off, k + off, vt + off, ctxb + off, lens, T_, 1, bx - NMAINB);
    }
}

// ---- LayerNorm in place on bf16: 1 wave per row, short8 loads, no barriers ----
__global__ void ln_kernel(bf16* __restrict__ x,
                          const float* __restrict__ g,
                          const float* __restrict__ b) {
    int wave = threadIdx.x >> 6, lane = threadIdx.x & 63;
    size_t row = (size_t)blockIdx.x * 4 + wave;
    bf16* xr = x + row * D_ + lane * 8;
    short8 v = *(const short8*)xr;
    float f[8];
    float s = 0.f;
#pragma unroll
    for (int j = 0; j < 8; ++j) { f[j] = b2f(v[j]); s += f[j]; }
#pragma unroll
    for (int m2 = 32; m2 > 0; m2 >>= 1) s += __shfl_xor(s, m2);
    float mu = s * (1.f / 512.f);
    float qv = 0.f;
#pragma unroll
    for (int j = 0; j < 8; ++j) { f[j] -= mu; qv += f[j] * f[j]; }
#pragma unroll
    for (int m2 = 32; m2 > 0; m2 >>= 1) qv += __shfl_xor(qv, m2);
    float inv = rsqrtf(qv * (1.f / 512.f) + 1e-5f);
    f32x4 g0 = *(const f32x4*)&g[lane * 8];
    f32x4 g1 = *(const f32x4*)&g[lane * 8 + 4];
    f32x4 b0 = *(const f32x4*)&b[lane * 8];
    f32x4 b1 = *(const f32x4*)&b[lane * 8 + 4];
    short8 o;
#pragma unroll
    for (int j = 0; j < 4; ++j) o[j] = (short)f2b(f[j] * inv * g0[j] + b0[j]);
#pragma unroll
    for (int j = 0; j < 4; ++j) o[j + 4] = (short)f2b(f[j + 4] * inv * g1[j] + b1[j]);
    *(short8*)xr = o;
}

__global__ void copy_last_main(const bf16* __restrict__ x, float* __restrict__ bh) {
    int idx = blockIdx.x * blockDim.x + threadIdx.x;  // 64*512
    int b = idx >> 9, d = idx & 511;
    bh[idx] = toF(x[(size_t)(b * S_ + S_ - 1) * D_ + d]);
}

__global__ void add_last_kernel(const bf16* __restrict__ x,
                                const int* __restrict__ lens,
                                float* __restrict__ sep) {
    int idx = blockIdx.x * blockDim.x + threadIdx.x;  // 384*512
    int bn = idx >> 9, d = idx & 511;
    int len = lens[bn];
    float add = (len > 0) ? toF(x[(size_t)(bn * T_ + len - 1) * D_ + d]) : 0.f;
    sep[idx] += add;
}

__global__ void final_kernel(const float* __restrict__ sep,
                             const float* __restrict__ bh,
                             const int* __restrict__ nflag,
                             float* __restrict__ out) {
    int bn = blockIdx.x;
    int b  = bn / NH_;
    int t  = threadIdx.x;  // 256
    __shared__ float red[256];
    float v0 = sep[(size_t)bn * D_ + t];
    float v1 = sep[(size_t)bn * D_ + t + 256];
    int nf = nflag[0];
    float scale = 1.f;
    if (nf) {
        v0 = fmaxf(v0, 0.f);
        v1 = fmaxf(v1, 0.f);
        red[t] = v0 * v0 + v1 * v1;
        __syncthreads();
        for (int off = 128; off > 0; off >>= 1) {
            if (t < off) red[t] += red[t + off];
            __syncthreads();
        }
        scale = 1.f / fmaxf(sqrtf(red[0]), 1e-12f);
        __syncthreads();
    }
    red[t] = v0 * scale * bh[(size_t)b * D_ + t] + v1 * scale * bh[(size_t)b * D_ + t + 256];
    __syncthreads();
    for (int off = 128; off > 0; off >>= 1) {
        if (t < off) red[t] += red[t + off];
        __syncthreads();
    }
    if (t == 0) out[bn] = red[0];
}

extern "C" void kernel_launch(void* const* d_in, const int* in_sizes, int n_in,
                              void* d_out, int out_size, void* d_ws, size_t ws_size,
                              hipStream_t stream) {
    const int*   segment   = (const int*)d_in[0];
    const int*   prev_hist = (const int*)d_in[1];
    const int*   lens      = (const int*)d_in[2];
    const float* sep_img   = (const float*)d_in[3];
    const int*   normalize = (const int*)d_in[4];
    const float* emb       = (const float*)d_in[5];
    const float* Wq = (const float*)d_in[6];
    const float* bq = (const float*)d_in[7];
    const float* Wk = (const float*)d_in[8];
    const float* bk = (const float*)d_in[9];
    const float* Wv = (const float*)d_in[10];
    const float* bv = (const float*)d_in[11];
    const float* Wo = (const float*)d_in[12];
    const float* bo = (const float*)d_in[13];
    const float* ln1g = (const float*)d_in[14];
    const float* ln1b = (const float*)d_in[15];
    const float* W1 = (const float*)d_in[16];
    const float* b1 = (const float*)d_in[17];
    const float* W2 = (const float*)d_in[18];
    const float* b2 = (const float*)d_in[19];
    const float* ln2g = (const float*)d_in[20];
    const float* ln2b = (const float*)d_in[21];
    const float* Wsep = (const float*)d_in[22];
    const float* bsep = (const float*)d_in[23];
    float* out = (float*)d_out;

    // ---- common small buffers + weights ----
    char* w = (char*)d_ws;
    float* bh   = (float*)w; w += (size_t)B_ * D_ * 4;
    float* sepb = (float*)w; w += (size_t)B_ * NH_ * D_ * 4;
    float* bqkv = (float*)w; w += (size_t)L_ * 1536 * 4;
    float* peT  = (float*)w; w += (size_t)S_ * D_ * 4;
    bf16* Wqkvt = (bf16*)w; w += (size_t)L_ * 1536 * D_ * 2;  // [l][n=1536][k=512]
    bf16* Wot = (bf16*)w; w += (size_t)L_ * D_ * D_ * 2;
    bf16* W1t = (bf16*)w; w += (size_t)L_ * D_ * FF_ * 2;
    bf16* W2t = (bf16*)w; w += (size_t)L_ * FF_ * D_ * 2;
    bf16* Wsept = (bf16*)w; w += (size_t)IMG_ * D_ * 2;

    size_t fixed = (size_t)(w - (char*)d_ws);
    // merged path: x16 + ctx + merged qkv (3 chunks of NTALL rows)
    size_t needM = (size_t)NTALL * D_ * 2 * 2 + QALL * 2 * 3;
    // combined path: x16 + ctx + 3 * QCHUNK
    size_t needA = (size_t)NTALL * D_ * 2 * 2 + QCHUNK * 2 * 3;
    bool merged   = (fixed + needM <= ws_size);
    bool combined = (fixed + needA <= ws_size);

    // ---- weight conversion + PE table (identical all paths) ----
    {
        dim3 tg(16, 16, L_);
        size_t qs = (size_t)1536 * D_;
        transpose_cast<<<tg, 256, 0, stream>>>(Wq, Wqkvt,             D_, D_, qs);
        transpose_cast<<<tg, 256, 0, stream>>>(Wk, Wqkvt + 512 * D_,  D_, D_, qs);
        transpose_cast<<<tg, 256, 0, stream>>>(Wv, Wqkvt + 1024 * D_, D_, D_, qs);
        transpose_cast<<<tg, 256, 0, stream>>>(Wo, Wot, D_, D_, (size_t)D_ * D_);
        transpose_cast<<<tg, 256, 0, stream>>>(W1, W1t, D_, FF_, (size_t)D_ * FF_);
        transpose_cast<<<tg, 256, 0, stream>>>(W2, W2t, FF_, D_, (size_t)FF_ * D_);
        transpose_cast<<<dim3(16, 64, 1), 256, 0, stream>>>(Wsep, Wsept, IMG_, D_,
                                                            (size_t)IMG_ * D_);
        gather_qkv_bias<<<(L_ * 1536 + 255) / 256, 256, 0, stream>>>(bq, bk, bv, bqkv);
        pe_kernel<<<(S_ * D_) / 256, 256, 0, stream>>>(peT);
    }

    if (merged) {
        // ---- merged layout: one qkv GEMM + one attn dispatch per layer ----
        bf16* x16  = (bf16*)w; w += (size_t)NTALL * D_ * 2;
        bf16* ctxb = (bf16*)w; w += (size_t)NTALL * D_ * 2;   // also ffmid
        bf16* qkvh = (bf16*)w; w += QALL * 2 * 3;             // q|k|v, each NTALL rows
        bf16* x16h  = x16  + (size_t)NTMAIN * D_;
        bf16* ffmid = ctxb;
        bf16* sep16 = qkvh;                                   // temp before first qkv

        // sep projection first (sep16 dead before first qkv GEMM)
        {
            int n = B_ * NH_ * IMG_;
            cast_bf16<<<(n + 255) / 256, 256, 0, stream>>>(sep_img, sep16, n);
            gemm_mfma<float><<<dim3(D_ / 128, (B_ * NH_) / 128), 256, 0, stream>>>(
                sep16, Wsept, bsep, sepb, B_ * NH_, D_, IMG_, -1, 0, 0, 0);
        }
        embed_kernel<<<(NTMAIN * D_ / 4) / 256, 256, 0, stream>>>(
            segment, emb, peT, x16, S_, NTMAIN * D_ / 4);
        embed_kernel<<<(NTHIST * D_ / 4) / 256, 256, 0, stream>>>(
            prev_hist, emb, peT, x16h, T_, NTHIST * D_ / 4);
        dim3 ga(D_ / 128, NTALL / 128);          // (4, 320)
        dim3 gq(1536 / 128, NTALL / 128);        // (12, 320)
        int attnBlocks = B_ * H_ * (S_ / 64) + B_ * NH_ * H_;  // 1024 + 1536
        for (int l = 0; l < L_; ++l) {
            size_t wl = (size_t)l * 1536 * D_;
            gemm_mfma<bf16><<<gq, 256, 0, stream>>>(
                x16, Wqkvt + wl, bqkv + l * 1536, qkvh, NTALL, 1536, D_, -2, 0, 0, 2);
            fused_attn2<<<attnBlocks, 256, 0, stream>>>(qkvh, ctxb, lens);
            gemm_mfma<bf16><<<ga, 256, 0, stream>>>(
                ctxb, Wot + (size_t)l * D_ * D_, bo + l * D_, x16,
                NTALL, D_, D_, -1, 0, 1, 0);  // += resid
            ln_kernel<<<NTALL / 4, 256, 0, stream>>>(x16, ln1g + l * D_, ln1b + l * D_);
            gemm_mfma<bf16><<<ga, 256, 0, stream>>>(
                x16, W1t + (size_t)l * D_ * FF_, b1 + l * FF_, ffmid,
                NTALL, FF_, D_, -1, 1, 0, 0);
            gemm_mfma<bf16><<<ga, 256, 0, stream>>>(
                ffmid, W2t + (size_t)l * FF_ * D_, b2 + l * D_, x16,
                NTALL, D_, FF_, -1, 0, 1, 0); // += resid
            ln_kernel<<<NTALL / 4, 256, 0, stream>>>(x16, ln2g + l * D_, ln2b + l * D_);
        }
        copy_last_main<<<(B_ * D_) / 256, 256, 0, stream>>>(x16, bh);
        add_last_kernel<<<(B_ * NH_ * D_) / 256, 256, 0, stream>>>(x16h, lens, sepb);
        final_kernel<<<B_ * NH_, 256, 0, stream>>>(sepb, bh, normalize, out);
    } else if (combined) {
        // ---- combined layout: shared qkv chunk, 2 qkv GEMMs/layer ----
        bf16* x16  = (bf16*)w; w += (size_t)NTALL * D_ * 2;
        bf16* ctxb = (bf16*)w; w += (size_t)NTALL * D_ * 2;   // also ffmid
        bf16* qh   = (bf16*)w; w += QCHUNK * 2;               // also sep16 temp
        bf16* kh   = (bf16*)w; w += QCHUNK * 2;
        bf16* vh   = (bf16*)w; w += QCHUNK * 2;
        bf16* x16h  = x16  + (size_t)NTMAIN * D_;
        bf16* ctxh  = ctxb + (size_t)NTMAIN * D_;
        bf16* ffmid = ctxb;
        bf16* sep16 = qh;

        {
            int n = B_ * NH_ * IMG_;
            cast_bf16<<<(n + 255) / 256, 256, 0, stream>>>(sep_img, sep16, n);
            gemm_mfma<float><<<dim3(D_ / 128, (B_ * NH_) / 128), 256, 0, stream>>>(
                sep16, Wsept, bsep, sepb, B_ * NH_, D_, IMG_, -1, 0, 0, 0);
        }
        embed_kernel<<<(NTMAIN * D_ / 4) / 256, 256, 0, stream>>>(
            segment, emb, peT, x16, S_, NTMAIN * D_ / 4);
        embed_kernel<<<(NTHIST * D_ / 4) / 256, 256, 0, stream>>>(
            prev_hist, emb, peT, x16h, T_, NTHIST * D_ / 4);
        dim3 ga(D_ / 128, NTALL / 128);          // (4, 320)
        for (int l = 0; l < L_; ++l) {
            size_t wl = (size_t)l * 1536 * D_;
            gemm_mfma<bf16><<<dim3(12, NTMAIN / 128), 256, 0, stream>>>(
                x16, Wqkvt + wl, bqkv + l * 1536, qh, NTMAIN, 1536, D_, 8, 0, 0, 2);
            fused_attn<<<B_ * H_ * (S_ / 64), 256, 0, stream>>>(
                qh, kh, vh, ctxb, nullptr, S_, S_ / 64);
            gemm_mfma<bf16><<<dim3(12, NTHIST / 128), 256, 0, stream>>>(
                x16h, Wqkvt + wl, bqkv + l * 1536, qh, NTHIST, 1536, D_, 6, 0, 0, 2);
            fused_attn<<<B_ * NH_ * H_ * (T_ / 64), 256, 0, stream>>>(
                qh, kh, vh, ctxh, lens, T_, T_ / 64);
            gemm_mfma<bf16><<<ga, 256, 0, stream>>>(
                ctxb, Wot + (size_t)l * D_ * D_, bo + l * D_, x16,
                NTALL, D_, D_, -1, 0, 1, 0);
            ln_kernel<<<NTALL / 4, 256, 0, stream>>>(x16, ln1g + l * D_, ln1b + l * D_);
            gemm_mfma<bf16><<<ga, 256, 0, stream>>>(
                x16, W1t + (size_t)l * D_ * FF_, b1 + l * FF_, ffmid,
                NTALL, FF_, D_, -1, 1, 0, 0);
            gemm_mfma<bf16><<<ga, 256, 0, stream>>>(
                ffmid, W2t + (size_t)l * FF_ * D_, b2 + l * D_, x16,
                NTALL, D_, FF_, -1, 0, 1, 0);
            ln_kernel<<<NTALL / 4, 256, 0, stream>>>(x16, ln2g + l * D_, ln2b + l * D_);
        }
        copy_last_main<<<(B_ * D_) / 256, 256, 0, stream>>>(x16, bh);
        add_last_kernel<<<(B_ * NH_ * D_) / 256, 256, 0, stream>>>(x16h, lens, sepb);
        final_kernel<<<B_ * NH_, 256, 0, stream>>>(sepb, bh, normalize, out);
    } else {
        // ---- fallback: split layout/behavior ----
        bf16* x16  = (bf16*)w; w += QCHUNK * 2;
        bf16* ctxb = (bf16*)w; w += QCHUNK * 2;
        bf16* qh   = (bf16*)w; w += QCHUNK * 2;
        bf16* kh   = (bf16*)w; w += QCHUNK * 2;
        bf16* vh   = (bf16*)w; w += QCHUNK * 2;
        bf16* sep16 = (bf16*)w; w += (size_t)B_ * NH_ * IMG_ * 2;
        bf16* ffmid = qh;

        {
            int n = B_ * NH_ * IMG_;
            cast_bf16<<<(n + 255) / 256, 256, 0, stream>>>(sep_img, sep16, n);
        }
        auto run_encoder = [&](int M, int Tt, int lt, const int* lens_p) {
            int NT = M * Tt;
            dim3 gg(D_ / 128, NT / 128);
            dim3 gq(1536 / 128, NT / 128);
            int nqt = Tt / 64;
            for (int l = 0; l < L_; ++l) {
                gemm_mfma<bf16><<<gq, 256, 0, stream>>>(
                    x16, Wqkvt + (size_t)l * 1536 * D_, bqkv + l * 1536, qh,
                    NT, 1536, D_, lt, 0, 0, 2);
                fused_attn<<<M * H_ * nqt, 256, 0, stream>>>(
                    qh, kh, vh, ctxb, lens_p, Tt, nqt);
                gemm_mfma<bf16><<<gg, 256, 0, stream>>>(
                    ctxb, Wot + (size_t)l * D_ * D_, bo + l * D_, x16,
                    NT, D_, D_, -1, 0, 1, 0);
                ln_kernel<<<NT / 4, 256, 0, stream>>>(x16, ln1g + l * D_, ln1b + l * D_);
                gemm_mfma<bf16><<<gg, 256, 0, stream>>>(
                    x16, W1t + (size_t)l * D_ * FF_, b1 + l * FF_, ffmid,
                    NT, FF_, D_, -1, 1, 0, 0);
                gemm_mfma<bf16><<<gg, 256, 0, stream>>>(
                    ffmid, W2t + (size_t)l * FF_ * D_, b2 + l * D_, x16,
                    NT, D_, FF_, -1, 0, 1, 0);
                ln_kernel<<<NT / 4, 256, 0, stream>>>(x16, ln2g + l * D_, ln2b + l * D_);
            }
        };
        embed_kernel<<<(NTMAIN * D_ / 4) / 256, 256, 0, stream>>>(
            segment, emb, peT, x16, S_, NTMAIN * D_ / 4);
        run_encoder(B_, S_, 8, nullptr);
        copy_last_main<<<(B_ * D_) / 256, 256, 0, stream>>>(x16, bh);
        gemm_mfma<float><<<dim3(D_ / 128, (B_ * NH_) / 128), 256, 0, stream>>>(
            sep16, Wsept, bsep, sepb, B_ * NH_, D_, IMG_, -1, 0, 0, 0);
        embed_kernel<<<(NTHIST * D_ / 4) / 256, 256, 0, stream>>>(
            prev_hist, emb, peT, x16, T_, NTHIST * D_ / 4);
        run_encoder(B_ * NH_, T_, 6, lens);
        add_last_kernel<<<(B_ * NH_ * D_) / 256, 256, 0, stream>>>(x16, lens, sepb);
        final_kernel<<<B_ * NH_, 256, 0, stream>>>(sepb, bh, normalize, out);
    }
}

// Round 7
// 1649.428 us; speedup vs baseline: 1.1228x; 1.1228x over previous
//
#include <hip/hip_runtime.h>
#include <hip/hip_bf16.h>
#include <math.h>

typedef __hip_bfloat16 bf16;
typedef __attribute__((ext_vector_type(8))) short short8;
typedef __attribute__((ext_vector_type(4))) short s16x4;
typedef __attribute__((ext_vector_type(4))) float f32x4;

#define D_    512
#define H_    4
#define DH_   128
#define L_    4
#define FF_   512
#define B_    64
#define NH_   6
#define S_    256
#define T_    64
#define IMG_  2048
#define NTMAIN (B_ * S_)              // 16384
#define NTHIST (B_ * NH_ * T_)        // 24576
#define NTALL  (NTMAIN + NTHIST)      // 40960
#define QCHUNK ((size_t)NTHIST * D_)  // element stride between q,k,v buffers (split path)
#define QALL   ((size_t)NTALL * D_)   // element stride between q,k,v buffers (merged path)

// async global->LDS, 16B per lane, LDS dest = wave-uniform base + lane*16
#define GLOAD_LDS(gp, lp) __builtin_amdgcn_global_load_lds( \
    (const __attribute__((address_space(1))) void*)(gp),    \
    (__attribute__((address_space(3))) void*)(lp), 16, 0, 0)

__device__ __forceinline__ float toF(bf16 v)  { return __bfloat162float(v); }
__device__ __forceinline__ float toF(float v) { return v; }
__device__ __forceinline__ void storeF(bf16* p, float v)  { *p = __float2bfloat16(v); }
__device__ __forceinline__ void storeF(float* p, float v) { *p = v; }

// round-to-nearest-even f32 -> bf16 bits
__device__ __forceinline__ unsigned short f2b(float f) {
    unsigned u = __float_as_uint(f);
    unsigned r = (u + 0x7fffu + ((u >> 16) & 1u)) >> 16;
    return (unsigned short)r;
}
// bf16 bits -> f32 (exact)
__device__ __forceinline__ float b2f(short b) {
    return __uint_as_float(((unsigned)(unsigned short)b) << 16);
}

// ---- merged weight transpose + cast: 7 weight tensors in ONE dispatch ----
// Each entry: src[R][512] fp32 -> dst[512][R] bf16 (z layers for R==512 entries).
// 1024 blocks per entry; entry = blockIdx.x >> 10.
struct PrepArgs {
    const float* src[7];
    bf16*        dst[7];
    size_t       dstride[7];
    int          R[7];        // 512 (z=4) or 2048 (z=1)
};
__global__ void prep_weights(PrepArgs a) {
    int e   = blockIdx.x >> 10;
    int id2 = blockIdx.x & 1023;
    const float* src = a.src[e];
    bf16* dst = a.dst[e];
    int R = a.R[e];
    int z, r0, c0;
    if (R == 512) {
        z = id2 >> 8;
        int yx = id2 & 255;
        r0 = (yx >> 4) * 32;
        c0 = (yx & 15) * 32;
    } else {            // Wsep: R=2048, single layer
        z = 0;
        r0 = (id2 >> 4) * 32;
        c0 = (id2 & 15) * 32;
    }
    src += (size_t)z * R * 512;
    dst += (size_t)z * a.dstride[e];
    __shared__ float t[32][33];
    int tx = threadIdx.x & 31, ty = threadIdx.x >> 5;   // 256 thr: ty 0..7
    for (int i = ty; i < 32; i += 8) t[i][tx] = src[(size_t)(r0 + i) * 512 + c0 + tx];
    __syncthreads();
    for (int i = ty; i < 32; i += 8)
        dst[(size_t)(c0 + i) * R + r0 + tx] = __float2bfloat16(t[tx][i]);
}

// ---- flat f32 -> bf16 cast ----
__global__ void cast_bf16(const float* __restrict__ src, bf16* __restrict__ dst, int n) {
    int i = blockIdx.x * blockDim.x + threadIdx.x;
    if (i < n) dst[i] = __float2bfloat16(src[i]);
}

// ---- gather qkv bias: o[l][0:512]=bq[l], [512:1024]=bk[l], [1024:1536]=bv[l] ----
__global__ void gather_qkv_bias(const float* __restrict__ bq, const float* __restrict__ bk,
                                const float* __restrict__ bv, float* __restrict__ o) {
    int idx = blockIdx.x * blockDim.x + threadIdx.x;  // L_*1536 = 6144
    if (idx >= L_ * 1536) return;
    int l = idx / 1536, j = idx - l * 1536;
    int which = j >> 9, rem = j & 511;
    const float* s = (which == 0) ? bq : (which == 1) ? bk : bv;
    o[idx] = s[l * 512 + rem];
}

// ---- positional-encoding table: pe[t][d], t < S_, d < D_ ----
__global__ void pe_kernel(float* __restrict__ pe) {
    int idx = blockIdx.x * blockDim.x + threadIdx.x;
    if (idx >= S_ * D_) return;
    int d = idx & (D_ - 1), t = idx >> 9;
    int i = d >> 1;
    float dv  = expf(-(float)(2 * i) * (9.210340371976184f / 512.0f));
    float ang = (float)t * dv;
    pe[idx] = (d & 1) ? cosf(ang) : sinf(ang);
}

// ---- embedding + PE-table add: 4 elems/thread, vectorized ----
__global__ void embed_kernel(const int* __restrict__ tokens,
                             const float* __restrict__ emb,
                             const float* __restrict__ pe,
                             bf16* __restrict__ x16,
                             int Tt, int total4) {
    int idx = blockIdx.x * blockDim.x + threadIdx.x;
    if (idx >= total4) return;
    int d4  = (idx & 127) * 4;      // D_/4 = 128 groups per row
    int row = idx >> 7;
    int t   = row & (Tt - 1);       // Tt is a power of two (256 or 64)
    int tok = tokens[row];
    f32x4 e = *(const f32x4*)&emb[(size_t)tok * D_ + d4];
    f32x4 p = *(const f32x4*)&pe[(size_t)t * D_ + d4];
    s16x4 o;
#pragma unroll
    for (int j = 0; j < 4; ++j) o[j] = (short)f2b(e[j] + p[j]);
    *(s16x4*)&x16[(size_t)row * D_ + d4] = o;
}

// ---- MFMA bf16 GEMM, 128x128 tile, 4 waves, proven round-5 core ----
// lt >= 0 : qkv scatter for a single encoder (row block size 1<<lt)
// lt == -1: plain row-major C (optional addC/relu)
// lt == -2: merged qkv scatter: rows < NTMAIN -> main (lt=8), else hist (lt=6),
//           q/k/v chunks strided by QALL, hist sub-offset NTMAIN*D_.
template <typename CT>
__global__ __launch_bounds__(256) void gemm_mfma(
    const bf16* __restrict__ A, const bf16* __restrict__ Bt,
    const float* __restrict__ bias, CT* __restrict__ C,
    int M, int N, int K, int lt, int relu, int addC, int vt) {
    __shared__ short As[128 * 64];
    __shared__ short Bs[128 * 64];
    int tid  = threadIdx.x;
    int wave = tid >> 6, lane = tid & 63, lr = lane & 15, quad = lane >> 4;
    int wr = (wave >> 1) * 64, wc = (wave & 1) * 64;
    int bx = blockIdx.x, by = blockIdx.y;
    if ((gridDim.y & 7) == 0) {
        int id = by * gridDim.x + bx;
        int xcd = id & 7, slot = id >> 3;
        by = xcd + 8 * (slot / gridDim.x);
        bx = slot % gridDim.x;
    }
    int row0 = by * 128, col0 = bx * 128;
    int srow   = lane >> 3;                    // 0..7 within 8-row segment
    int gchunk = (lane & 7) ^ srow;            // XOR-swizzled source chunk
    f32x4 acc[4][4];
    f32x4 zz = {0.f, 0.f, 0.f, 0.f};
#pragma unroll
    for (int mi = 0; mi < 4; ++mi)
#pragma unroll
        for (int ni = 0; ni < 4; ++ni) acc[mi][ni] = zz;

    int lr7 = lr & 7;
    for (int kt = 0; kt < K; kt += 64) {
#pragma unroll
        for (int sseg = 0; sseg < 4; ++sseg) {
            int s = wave + sseg * 4;           // segment 0..15
            int rloc = s * 8 + srow;
            const bf16* gA = &A[(size_t)(row0 + rloc) * K + kt + gchunk * 8];
            const bf16* gB = &Bt[(size_t)(col0 + rloc) * K + kt + gchunk * 8];
            GLOAD_LDS(gA, &As[s * 512]);
            GLOAD_LDS(gB, &Bs[s * 512]);
        }
        __syncthreads();   // drains vmcnt (async LDS writes) + barrier
#pragma unroll
        for (int ks = 0; ks < 2; ++ks) {
            int cp = (((ks * 4) + quad) ^ lr7) * 8;
            short8 af[4], bf4[4];
#pragma unroll
            for (int mi = 0; mi < 4; ++mi)
                af[mi] = *(const short8*)&As[(wr + mi * 16 + lr) * 64 + cp];
#pragma unroll
            for (int ni = 0; ni < 4; ++ni)
                bf4[ni] = *(const short8*)&Bs[(wc + ni * 16 + lr) * 64 + cp];
#pragma unroll
            for (int mi = 0; mi < 4; ++mi)
#pragma unroll
                for (int ni = 0; ni < 4; ++ni)
                    acc[mi][ni] = __builtin_amdgcn_mfma_f32_16x16x32_bf16(
                        af[mi], bf4[ni], acc[mi][ni], 0, 0, 0);
        }
        __syncthreads();   // protect LDS reuse before next iteration's async writes
    }
#pragma unroll
    for (int ni = 0; ni < 4; ++ni) {
        int gc = col0 + wc + ni * 16 + lr;
        float bi = bias[gc];
#pragma unroll
        for (int mi = 0; mi < 4; ++mi) {
            int gr0 = row0 + wr + mi * 16 + quad * 4;
            f32x4 vv = acc[mi][ni];
            if (lt != -1) {
                // qkv scatter path (bf16 C only in practice)
                int ltl = (lt == -2) ? ((gr0 < NTMAIN) ? 8 : 6) : lt;
                size_t qstr = (lt == -2) ? QALL : QCHUNK;
                size_t sub  = (lt == -2 && gr0 >= NTMAIN) ? (size_t)NTMAIN * D_ : 0;
                int rb      = (lt == -2 && gr0 >= NTMAIN) ? gr0 - NTMAIN : gr0;
                int which = gc >> 9;              // 0=q,1=k,2=v (fused qkv)
                int h2 = (gc >> 7) & 3, dh = gc & 127;
                size_t base = (size_t)which * qstr + sub;
                int Tm = (1 << ltl) - 1;
                if (which == 2) {
                    // v layout: consecutive qi contiguous -> one 8B store
                    int mq = rb >> ltl, qi0 = rb & Tm;   // rb aligned 4
                    size_t oi0 = base + ((((size_t)(mq * H_ + h2)) * DH_ + dh) << ltl) + qi0;
                    s16x4 o;
#pragma unroll
                    for (int rr = 0; rr < 4; ++rr) o[rr] = (short)f2b(vv[rr] + bi);
                    *(s16x4*)((bf16*)C + oi0) = o;
                } else {
#pragma unroll
                    for (int rr = 0; rr < 4; ++rr) {
                        int r = rb + rr;
                        int mq = r >> ltl, qi = r & Tm;
                        size_t oi = base + ((((size_t)(mq * H_ + h2)) << ltl) + qi) * DH_ + dh;
                        storeF(&C[oi], vv[rr] + bi);
                    }
                }
            } else {
#pragma unroll
                for (int rr = 0; rr < 4; ++rr) {
                    int r = gr0 + rr;
                    float val = vv[rr] + bi;
                    size_t oi = (size_t)r * N + gc;
                    if (addC) val += toF(C[oi]);
                    if (relu) val = fmaxf(val, 0.f);
                    storeF(&C[oi], val);
                }
            }
        }
    }
}

// ---- MFMA flash attention: shared body, two entry points ----
struct AttnSmem {
    short Ks[64][136];
    short Vs[128][72];
    short Ps[4][16][72];
};

__device__ __forceinline__ void attn_body(
    AttnSmem& sm,
    const bf16* __restrict__ q, const bf16* __restrict__ k, const bf16* __restrict__ vt,
    bf16* __restrict__ ctx, const int* __restrict__ lens, int Tt, int nqt, int bx) {
    int qt = bx % nqt, mh = bx / nqt;
    int m = mh >> 2, h = mh & 3;
    int tid  = threadIdx.x;
    int wave = tid >> 6, lane = tid & 63, lr = lane & 15, quad = lane >> 4;
    int q0 = qt * 64;
    int kvalid = Tt;
    if (lens) { int l0 = lens[m]; kvalid = l0 < 1 ? 1 : l0; }

    short8 aq[4];
    const bf16* qrow = q + ((size_t)mh * Tt + q0 + wave * 16 + lr) * DH_;
#pragma unroll
    for (int ks2 = 0; ks2 < 4; ++ks2)
        aq[ks2] = *(const short8*)&qrow[ks2 * 32 + quad * 8];

    float mrow[4], lrow[4];
#pragma unroll
    for (int r = 0; r < 4; ++r) { mrow[r] = -INFINITY; lrow[r] = 0.f; }
    f32x4 acco[8];
    f32x4 zz = {0.f, 0.f, 0.f, 0.f};
#pragma unroll
    for (int n = 0; n < 8; ++n) acco[n] = zz;

    int nkt = Tt >> 6;
    for (int kt = 0; kt < nkt; ++kt) {
        int kb = kt * 64;
        __syncthreads();
#pragma unroll
        for (int ee = 0; ee < 4; ++ee) {
            int e = tid + ee * 256;
            int r = e >> 4, c = (e & 15) * 8;
            *(short8*)&sm.Ks[r][c] = *(const short8*)&k[((size_t)mh * Tt + kb + r) * DH_ + c];
        }
#pragma unroll
        for (int ee = 0; ee < 4; ++ee) {
            int e = tid + ee * 256;
            int r = e >> 3, c = (e & 7) * 8;
            *(short8*)&sm.Vs[r][c] = *(const short8*)&vt[((size_t)mh * DH_ + r) * Tt + kb + c];
        }
        __syncthreads();
        f32x4 s[4];
#pragma unroll
        for (int ni = 0; ni < 4; ++ni) s[ni] = zz;
#pragma unroll
        for (int ni = 0; ni < 4; ++ni)
#pragma unroll
            for (int ks2 = 0; ks2 < 4; ++ks2) {
                short8 kf = *(const short8*)&sm.Ks[ni * 16 + lr][ks2 * 32 + quad * 8];
                s[ni] = __builtin_amdgcn_mfma_f32_16x16x32_bf16(aq[ks2], kf, s[ni], 0, 0, 0);
            }
        float mx[4] = {-INFINITY, -INFINITY, -INFINITY, -INFINITY};
#pragma unroll
        for (int ni = 0; ni < 4; ++ni) {
            bool ok = (kb + ni * 16 + lr) < kvalid;
#pragma unroll
            for (int reg = 0; reg < 4; ++reg) {
                float v = s[ni][reg] * 0.08838834764831845f;
                v = ok ? v : -INFINITY;
                s[ni][reg] = v;
                mx[reg] = fmaxf(mx[reg], v);
            }
        }
#pragma unroll
        for (int d2 = 1; d2 < 16; d2 <<= 1)
#pragma unroll
            for (int reg = 0; reg < 4; ++reg)
                mx[reg] = fmaxf(mx[reg], __shfl_xor(mx[reg], d2));
        float alpha[4];
#pragma unroll
        for (int reg = 0; reg < 4; ++reg) {
            float mn = fmaxf(mrow[reg], mx[reg]);
            alpha[reg] = __expf(mrow[reg] - mn);
            mrow[reg] = mn;
        }
        float rs[4] = {0.f, 0.f, 0.f, 0.f};
#pragma unroll
        for (int ni = 0; ni < 4; ++ni)
#pragma unroll
            for (int reg = 0; reg < 4; ++reg) {
                float p = __expf(s[ni][reg] - mrow[reg]);
                s[ni][reg] = p;
                rs[reg] += p;
            }
#pragma unroll
        for (int d2 = 1; d2 < 16; d2 <<= 1)
#pragma unroll
            for (int reg = 0; reg < 4; ++reg)
                rs[reg] += __shfl_xor(rs[reg], d2);
#pragma unroll
        for (int reg = 0; reg < 4; ++reg)
            lrow[reg] = lrow[reg] * alpha[reg] + rs[reg];
#pragma unroll
        for (int ni = 0; ni < 4; ++ni)
#pragma unroll
            for (int reg = 0; reg < 4; ++reg)
                sm.Ps[wave][quad * 4 + reg][ni * 16 + lr] = (short)f2b(s[ni][reg]);
#pragma unroll
        for (int n = 0; n < 8; ++n)
#pragma unroll
            for (int reg = 0; reg < 4; ++reg) acco[n][reg] *= alpha[reg];
#pragma unroll
        for (int ks2 = 0; ks2 < 2; ++ks2) {
            short8 pf = *(const short8*)&sm.Ps[wave][lr][ks2 * 32 + quad * 8];
#pragma unroll
            for (int n = 0; n < 8; ++n) {
                short8 vf = *(const short8*)&sm.Vs[n * 16 + lr][ks2 * 32 + quad * 8];
                acco[n] = __builtin_amdgcn_mfma_f32_16x16x32_bf16(pf, vf, acco[n], 0, 0, 0);
            }
        }
    }
    float linv[4];
#pragma unroll
    for (int reg = 0; reg < 4; ++reg) linv[reg] = 1.f / lrow[reg];
#pragma unroll
    for (int n = 0; n < 8; ++n)
#pragma unroll
        for (int reg = 0; reg < 4; ++reg) {
            int qq = q0 + wave * 16 + quad * 4 + reg;
            ctx[((size_t)m * Tt + qq) * D_ + h * DH_ + n * 16 + lr] =
                __float2bfloat16(acco[n][reg] * linv[reg]);
        }
}

// standalone (split/fallback path)
__global__ __launch_bounds__(256) void fused_attn(
    const bf16* __restrict__ q, const bf16* __restrict__ k, const bf16* __restrict__ vt,
    bf16* __restrict__ ctx, const int* __restrict__ lens, int Tt, int nqt) {
    __shared__ AttnSmem sm;
    attn_body(sm, q, k, vt, ctx, lens, Tt, nqt, blockIdx.x);
}

// merged main+hist attention: blocks [0,1024) main, [1024,2560) hist
__global__ __launch_bounds__(256) void fused_attn2(
    const bf16* __restrict__ qkv, bf16* __restrict__ ctxb, const int* __restrict__ lens) {
    __shared__ AttnSmem sm;
    int bx = blockIdx.x;
    const bf16* q  = qkv;
    const bf16* k  = qkv + QALL;
    const bf16* vt = qkv + 2 * QALL;
    const int NMAINB = B_ * H_ * (S_ / 64);   // 1024
    if (bx < NMAINB) {
        attn_body(sm, q, k, vt, ctxb, nullptr, S_, S_ / 64, bx);
    } else {
        size_t off = (size_t)NTMAIN * D_;
        attn_body(sm, q + off, k + off, vt + off, ctxb + off, lens, T_, 1, bx - NMAINB);
    }
}

// ---- LayerNorm in place on bf16: 1 wave per row, short8 loads, no barriers ----
__global__ void ln_kernel(bf16* __restrict__ x,
                          const float* __restrict__ g,
                          const float* __restrict__ b) {
    int wave = threadIdx.x >> 6, lane = threadIdx.x & 63;
    size_t row = (size_t)blockIdx.x * 4 + wave;
    bf16* xr = x + row * D_ + lane * 8;
    short8 v = *(const short8*)xr;
    float f[8];
    float s = 0.f;
#pragma unroll
    for (int j = 0; j < 8; ++j) { f[j] = b2f(v[j]); s += f[j]; }
#pragma unroll
    for (int m2 = 32; m2 > 0; m2 >>= 1) s += __shfl_xor(s, m2);
    float mu = s * (1.f / 512.f);
    float qv = 0.f;
#pragma unroll
    for (int j = 0; j < 8; ++j) { f[j] -= mu; qv += f[j] * f[j]; }
#pragma unroll
    for (int m2 = 32; m2 > 0; m2 >>= 1) qv += __shfl_xor(qv, m2);
    float inv = rsqrtf(qv * (1.f / 512.f) + 1e-5f);
    f32x4 g0 = *(const f32x4*)&g[lane * 8];
    f32x4 g1 = *(const f32x4*)&g[lane * 8 + 4];
    f32x4 b0 = *(const f32x4*)&b[lane * 8];
    f32x4 b1 = *(const f32x4*)&b[lane * 8 + 4];
    short8 o;
#pragma unroll
    for (int j = 0; j < 4; ++j) o[j] = (short)f2b(f[j] * inv * g0[j] + b0[j]);
#pragma unroll
    for (int j = 0; j < 4; ++j) o[j + 4] = (short)f2b(f[j + 4] * inv * g1[j] + b1[j]);
    *(short8*)xr = o;
}

__global__ void copy_last_main(const bf16* __restrict__ x, float* __restrict__ bh) {
    int idx = blockIdx.x * blockDim.x + threadIdx.x;  // 64*512
    int b = idx >> 9, d = idx & 511;
    bh[idx] = toF(x[(size_t)(b * S_ + S_ - 1) * D_ + d]);
}

__global__ void add_last_kernel(const bf16* __restrict__ x,
                                const int* __restrict__ lens,
                                float* __restrict__ sep) {
    int idx = blockIdx.x * blockDim.x + threadIdx.x;  // 384*512
    int bn = idx >> 9, d = idx & 511;
    int len = lens[bn];
    float add = (len > 0) ? toF(x[(size_t)(bn * T_ + len - 1) * D_ + d]) : 0.f;
    sep[idx] += add;
}

__global__ void final_kernel(const float* __restrict__ sep,
                             const float* __restrict__ bh,
                             const int* __restrict__ nflag,
                             float* __restrict__ out) {
    int bn = blockIdx.x;
    int b  = bn / NH_;
    int t  = threadIdx.x;  // 256
    __shared__ float red[256];
    float v0 = sep[(size_t)bn * D_ + t];
    float v1 = sep[(size_t)bn * D_ + t + 256];
    int nf = nflag[0];
    float scale = 1.f;
    if (nf) {
        v0 = fmaxf(v0, 0.f);
        v1 = fmaxf(v1, 0.f);
        red[t] = v0 * v0 + v1 * v1;
        __syncthreads();
        for (int off = 128; off > 0; off >>= 1) {
            if (t < off) red[t] += red[t + off];
            __syncthreads();
        }
        scale = 1.f / fmaxf(sqrtf(red[0]), 1e-12f);
        __syncthreads();
    }
    red[t] = v0 * scale * bh[(size_t)b * D_ + t] + v1 * scale * bh[(size_t)b * D_ + t + 256];
    __syncthreads();
    for (int off = 128; off > 0; off >>= 1) {
        if (t < off) red[t] += red[t + off];
        __syncthreads();
    }
    if (t == 0) out[bn] = red[0];
}

extern "C" void kernel_launch(void* const* d_in, const int* in_sizes, int n_in,
                              void* d_out, int out_size, void* d_ws, size_t ws_size,
                              hipStream_t stream) {
    const int*   segment   = (const int*)d_in[0];
    const int*   prev_hist = (const int*)d_in[1];
    const int*   lens      = (const int*)d_in[2];
    const float* sep_img   = (const float*)d_in[3];
    const int*   normalize = (const int*)d_in[4];
    const float* emb       = (const float*)d_in[5];
    const float* Wq = (const float*)d_in[6];
    const float* bq = (const float*)d_in[7];
    const float* Wk = (const float*)d_in[8];
    const float* bk = (const float*)d_in[9];
    const float* Wv = (const float*)d_in[10];
    const float* bv = (const float*)d_in[11];
    const float* Wo = (const float*)d_in[12];
    const float* bo = (const float*)d_in[13];
    const float* ln1g = (const float*)d_in[14];
    const float* ln1b = (const float*)d_in[15];
    const float* W1 = (const float*)d_in[16];
    const float* b1 = (const float*)d_in[17];
    const float* W2 = (const float*)d_in[18];
    const float* b2 = (const float*)d_in[19];
    const float* ln2g = (const float*)d_in[20];
    const float* ln2b = (const float*)d_in[21];
    const float* Wsep = (const float*)d_in[22];
    const float* bsep = (const float*)d_in[23];
    float* out = (float*)d_out;

    // ---- common small buffers + weights ----
    char* w = (char*)d_ws;
    float* bh   = (float*)w; w += (size_t)B_ * D_ * 4;
    float* sepb = (float*)w; w += (size_t)B_ * NH_ * D_ * 4;
    float* bqkv = (float*)w; w += (size_t)L_ * 1536 * 4;
    float* peT  = (float*)w; w += (size_t)S_ * D_ * 4;
    bf16* Wqkvt = (bf16*)w; w += (size_t)L_ * 1536 * D_ * 2;  // [l][n=1536][k=512]
    bf16* Wot = (bf16*)w; w += (size_t)L_ * D_ * D_ * 2;
    bf16* W1t = (bf16*)w; w += (size_t)L_ * D_ * FF_ * 2;
    bf16* W2t = (bf16*)w; w += (size_t)L_ * FF_ * D_ * 2;
    bf16* Wsept = (bf16*)w; w += (size_t)IMG_ * D_ * 2;

    size_t fixed = (size_t)(w - (char*)d_ws);
    // merged path: x16 + ctx + merged qkv (3 chunks of NTALL rows)
    size_t needM = (size_t)NTALL * D_ * 2 * 2 + QALL * 2 * 3;
    // combined path: x16 + ctx + 3 * QCHUNK
    size_t needA = (size_t)NTALL * D_ * 2 * 2 + QCHUNK * 2 * 3;
    bool merged   = (fixed + needM <= ws_size);
    bool combined = (fixed + needA <= ws_size);

    // ---- weight conversion (single dispatch) + PE table + bias gather ----
    {
        PrepArgs pa;
        pa.src[0] = Wq;   pa.dst[0] = Wqkvt;              pa.dstride[0] = (size_t)1536 * D_; pa.R[0] = 512;
        pa.src[1] = Wk;   pa.dst[1] = Wqkvt + 512 * D_;   pa.dstride[1] = (size_t)1536 * D_; pa.R[1] = 512;
        pa.src[2] = Wv;   pa.dst[2] = Wqkvt + 1024 * D_;  pa.dstride[2] = (size_t)1536 * D_; pa.R[2] = 512;
        pa.src[3] = Wo;   pa.dst[3] = Wot;                pa.dstride[3] = (size_t)D_ * D_;   pa.R[3] = 512;
        pa.src[4] = W1;   pa.dst[4] = W1t;                pa.dstride[4] = (size_t)D_ * FF_;  pa.R[4] = 512;
        pa.src[5] = W2;   pa.dst[5] = W2t;                pa.dstride[5] = (size_t)FF_ * D_;  pa.R[5] = 512;
        pa.src[6] = Wsep; pa.dst[6] = Wsept;              pa.dstride[6] = 0;                 pa.R[6] = 2048;
        prep_weights<<<7 * 1024, 256, 0, stream>>>(pa);
        gather_qkv_bias<<<(L_ * 1536 + 255) / 256, 256, 0, stream>>>(bq, bk, bv, bqkv);
        pe_kernel<<<(S_ * D_) / 256, 256, 0, stream>>>(peT);
    }

    if (merged) {
        // ---- merged layout: one qkv GEMM + one attn dispatch per layer ----
        bf16* x16  = (bf16*)w; w += (size_t)NTALL * D_ * 2;
        bf16* ctxb = (bf16*)w; w += (size_t)NTALL * D_ * 2;   // also ffmid
        bf16* qkvh = (bf16*)w; w += QALL * 2 * 3;             // q|k|v, each NTALL rows
        bf16* x16h  = x16  + (size_t)NTMAIN * D_;
        bf16* ffmid = ctxb;
        bf16* sep16 = qkvh;                                   // temp before first qkv

        // sep projection first (sep16 dead before first qkv GEMM)
        {
            int n = B_ * NH_ * IMG_;
            cast_bf16<<<(n + 255) / 256, 256, 0, stream>>>(sep_img, sep16, n);
            gemm_mfma<float><<<dim3(D_ / 128, (B_ * NH_) / 128), 256, 0, stream>>>(
                sep16, Wsept, bsep, sepb, B_ * NH_, D_, IMG_, -1, 0, 0, 0);
        }
        embed_kernel<<<(NTMAIN * D_ / 4) / 256, 256, 0, stream>>>(
            segment, emb, peT, x16, S_, NTMAIN * D_ / 4);
        embed_kernel<<<(NTHIST * D_ / 4) / 256, 256, 0, stream>>>(
            prev_hist, emb, peT, x16h, T_, NTHIST * D_ / 4);
        dim3 ga(D_ / 128, NTALL / 128);          // (4, 320)
        dim3 gq(1536 / 128, NTALL / 128);        // (12, 320)
        int attnBlocks = B_ * H_ * (S_ / 64) + B_ * NH_ * H_;  // 1024 + 1536
        for (int l = 0; l < L_; ++l) {
            size_t wl = (size_t)l * 1536 * D_;
            gemm_mfma<bf16><<<gq, 256, 0, stream>>>(
                x16, Wqkvt + wl, bqkv + l * 1536, qkvh, NTALL, 1536, D_, -2, 0, 0, 2);
            fused_attn2<<<attnBlocks, 256, 0, stream>>>(qkvh, ctxb, lens);
            gemm_mfma<bf16><<<ga, 256, 0, stream>>>(
                ctxb, Wot + (size_t)l * D_ * D_, bo + l * D_, x16,
                NTALL, D_, D_, -1, 0, 1, 0);  // += resid
            ln_kernel<<<NTALL / 4, 256, 0, stream>>>(x16, ln1g + l * D_, ln1b + l * D_);
            gemm_mfma<bf16><<<ga, 256, 0, stream>>>(
                x16, W1t + (size_t)l * D_ * FF_, b1 + l * FF_, ffmid,
                NTALL, FF_, D_, -1, 1, 0, 0);
            gemm_mfma<bf16><<<ga, 256, 0, stream>>>(
                ffmid, W2t + (size_t)l * FF_ * D_, b2 + l * D_, x16,
                NTALL, D_, FF_, -1, 0, 1, 0); // += resid
            ln_kernel<<<NTALL / 4, 256, 0, stream>>>(x16, ln2g + l * D_, ln2b + l * D_);
        }
        copy_last_main<<<(B_ * D_) / 256, 256, 0, stream>>>(x16, bh);
        add_last_kernel<<<(B_ * NH_ * D_) / 256, 256, 0, stream>>>(x16h, lens, sepb);
        final_kernel<<<B_ * NH_, 256, 0, stream>>>(sepb, bh, normalize, out);
    } else if (combined) {
        // ---- combined layout: shared qkv chunk, 2 qkv GEMMs/layer ----
        bf16* x16  = (bf16*)w; w += (size_t)NTALL * D_ * 2;
        bf16* ctxb = (bf16*)w; w += (size_t)NTALL * D_ * 2;   // also ffmid
        bf16* qh   = (bf16*)w; w += QCHUNK * 2;               // also sep16 temp
        bf16* kh   = (bf16*)w; w += QCHUNK * 2;
        bf16* vh   = (bf16*)w; w += QCHUNK * 2;
        bf16* x16h  = x16  + (size_t)NTMAIN * D_;
        bf16* ctxh  = ctxb + (size_t)NTMAIN * D_;
        bf16* ffmid = ctxb;
        bf16* sep16 = qh;

        {
            int n = B_ * NH_ * IMG_;
            cast_bf16<<<(n + 255) / 256, 256, 0, stream>>>(sep_img, sep16, n);
            gemm_mfma<float><<<dim3(D_ / 128, (B_ * NH_) / 128), 256, 0, stream>>>(
                sep16, Wsept, bsep, sepb, B_ * NH_, D_, IMG_, -1, 0, 0, 0);
        }
        embed_kernel<<<(NTMAIN * D_ / 4) / 256, 256, 0, stream>>>(
            segment, emb, peT, x16, S_, NTMAIN * D_ / 4);
        embed_kernel<<<(NTHIST * D_ / 4) / 256, 256, 0, stream>>>(
            prev_hist, emb, peT, x16h, T_, NTHIST * D_ / 4);
        dim3 ga(D_ / 128, NTALL / 128);          // (4, 320)
        for (int l = 0; l < L_; ++l) {
            size_t wl = (size_t)l * 1536 * D_;
            gemm_mfma<bf16><<<dim3(12, NTMAIN / 128), 256, 0, stream>>>(
                x16, Wqkvt + wl, bqkv + l * 1536, qh, NTMAIN, 1536, D_, 8, 0, 0, 2);
            fused_attn<<<B_ * H_ * (S_ / 64), 256, 0, stream>>>(
                qh, kh, vh, ctxb, nullptr, S_, S_ / 64);
            gemm_mfma<bf16><<<dim3(12, NTHIST / 128), 256, 0, stream>>>(
                x16h, Wqkvt + wl, bqkv + l * 1536, qh, NTHIST, 1536, D_, 6, 0, 0, 2);
            fused_attn<<<B_ * NH_ * H_ * (T_ / 64), 256, 0, stream>>>(
                qh, kh, vh, ctxh, lens, T_, T_ / 64);
            gemm_mfma<bf16><<<ga, 256, 0, stream>>>(
                ctxb, Wot + (size_t)l * D_ * D_, bo + l * D_, x16,
                NTALL, D_, D_, -1, 0, 1, 0);
            ln_kernel<<<NTALL / 4, 256, 0, stream>>>(x16, ln1g + l * D_, ln1b + l * D_);
            gemm_mfma<bf16><<<ga, 256, 0, stream>>>(
                x16, W1t + (size_t)l * D_ * FF_, b1 + l * FF_, ffmid,
                NTALL, FF_, D_, -1, 1, 0, 0);
            gemm_mfma<bf16><<<ga, 256, 0, stream>>>(
                ffmid, W2t + (size_t)l * FF_ * D_, b2 + l * D_, x16,
                NTALL, D_, FF_, -1, 0, 1, 0);
            ln_kernel<<<NTALL / 4, 256, 0, stream>>>(x16, ln2g + l * D_, ln2b + l * D_);
        }
        copy_last_main<<<(B_ * D_) / 256, 256, 0, stream>>>(x16, bh);
        add_last_kernel<<<(B_ * NH_ * D_) / 256, 256, 0, stream>>>(x16h, lens, sepb);
        final_kernel<<<B_ * NH_, 256, 0, stream>>>(sepb, bh, normalize, out);
    } else {
        // ---- fallback: split layout/behavior ----
        bf16* x16  = (bf16*)w; w += QCHUNK * 2;
        bf16* ctxb = (bf16*)w; w += QCHUNK * 2;
        bf16* qh   = (bf16*)w; w += QCHUNK * 2;
        bf16* kh   = (bf16*)w; w += QCHUNK * 2;
        bf16* vh   = (bf16*)w; w += QCHUNK * 2;
        bf16* sep16 = (bf16*)w; w += (size_t)B_ * NH_ * IMG_ * 2;
        bf16* ffmid = qh;

        {
            int n = B_ * NH_ * IMG_;
            cast_bf16<<<(n + 255) / 256, 256, 0, stream>>>(sep_img, sep16, n);
        }
        auto run_encoder = [&](int M, int Tt, int lt, const int* lens_p) {
            int NT = M * Tt;
            dim3 gg(D_ / 128, NT / 128);
            dim3 gq(1536 / 128, NT / 128);
            int nqt = Tt / 64;
            for (int l = 0; l < L_; ++l) {
                gemm_mfma<bf16><<<gq, 256, 0, stream>>>(
                    x16, Wqkvt + (size_t)l * 1536 * D_, bqkv + l * 1536, qh,
                    NT, 1536, D_, lt, 0, 0, 2);
                fused_attn<<<M * H_ * nqt, 256, 0, stream>>>(
                    qh, kh, vh, ctxb, lens_p, Tt, nqt);
                gemm_mfma<bf16><<<gg, 256, 0, stream>>>(
                    ctxb, Wot + (size_t)l * D_ * D_, bo + l * D_, x16,
                    NT, D_, D_, -1, 0, 1, 0);
                ln_kernel<<<NT / 4, 256, 0, stream>>>(x16, ln1g + l * D_, ln1b + l * D_);
                gemm_mfma<bf16><<<gg, 256, 0, stream>>>(
                    x16, W1t + (size_t)l * D_ * FF_, b1 + l * FF_, ffmid,
                    NT, FF_, D_, -1, 1, 0, 0);
                gemm_mfma<bf16><<<gg, 256, 0, stream>>>(
                    ffmid, W2t + (size_t)l * FF_ * D_, b2 + l * D_, x16,
                    NT, D_, FF_, -1, 0, 1, 0);
                ln_kernel<<<NT / 4, 256, 0, stream>>>(x16, ln2g + l * D_, ln2b + l * D_);
            }
        };
        embed_kernel<<<(NTMAIN * D_ / 4) / 256, 256, 0, stream>>>(
            segment, emb, peT, x16, S_, NTMAIN * D_ / 4);
        run_encoder(B_, S_, 8, nullptr);
        copy_last_main<<<(B_ * D_) / 256, 256, 0, stream>>>(x16, bh);
        gemm_mfma<float><<<dim3(D_ / 128, (B_ * NH_) / 128), 256, 0, stream>>>(
            sep16, Wsept, bsep, sepb, B_ * NH_, D_, IMG_, -1, 0, 0, 0);
        embed_kernel<<<(NTHIST * D_ / 4) / 256, 256, 0, stream>>>(
            prev_hist, emb, peT, x16, T_, NTHIST * D_ / 4);
        run_encoder(B_ * NH_, T_, 6, lens);
        add_last_kernel<<<(B_ * NH_ * D_) / 256, 256, 0, stream>>>(x16, lens, sepb);
        final_kernel<<<B_ * NH_, 256, 0, stream>>>(sepb, bh, normalize, out);
    }
}

// Round 8
// 1613.153 us; speedup vs baseline: 1.1480x; 1.0225x over previous
//
#include <hip/hip_runtime.h>
#include <hip/hip_bf16.h>
#include <math.h>

typedef __hip_bfloat16 bf16;
typedef __attribute__((ext_vector_type(8))) short short8;
typedef __attribute__((ext_vector_type(4))) short s16x4;
typedef __attribute__((ext_vector_type(4))) float f32x4;

#define D_    512
#define H_    4
#define DH_   128
#define L_    4
#define FF_   512
#define B_    64
#define NH_   6
#define S_    256
#define T_    64
#define IMG_  2048
#define NTMAIN (B_ * S_)              // 16384
#define NTHIST (B_ * NH_ * T_)        // 24576
#define NTALL  (NTMAIN + NTHIST)      // 40960
#define QCHUNK ((size_t)NTHIST * D_)  // element stride between q,k,v buffers (split path)
#define QALL   ((size_t)NTALL * D_)   // element stride between q,k,v buffers (merged path)

// async global->LDS, 16B per lane, LDS dest = wave-uniform base + lane*16
#define GLOAD_LDS(gp, lp) __builtin_amdgcn_global_load_lds( \
    (const __attribute__((address_space(1))) void*)(gp),    \
    (__attribute__((address_space(3))) void*)(lp), 16, 0, 0)

__device__ __forceinline__ float toF(bf16 v)  { return __bfloat162float(v); }
__device__ __forceinline__ float toF(float v) { return v; }
__device__ __forceinline__ void storeF(bf16* p, float v)  { *p = __float2bfloat16(v); }
__device__ __forceinline__ void storeF(float* p, float v) { *p = v; }

// round-to-nearest-even f32 -> bf16 bits
__device__ __forceinline__ unsigned short f2b(float f) {
    unsigned u = __float_as_uint(f);
    unsigned r = (u + 0x7fffu + ((u >> 16) & 1u)) >> 16;
    return (unsigned short)r;
}
// bf16 bits -> f32 (exact)
__device__ __forceinline__ float b2f(short b) {
    return __uint_as_float(((unsigned)(unsigned short)b) << 16);
}

// ---- merged weight transpose + cast: 7 weight tensors in ONE dispatch ----
struct PrepArgs {
    const float* src[7];
    bf16*        dst[7];
    size_t       dstride[7];
    int          R[7];        // 512 (z=4) or 2048 (z=1)
};
__global__ void prep_weights(PrepArgs a) {
    int e   = blockIdx.x >> 10;
    int id2 = blockIdx.x & 1023;
    const float* src = a.src[e];
    bf16* dst = a.dst[e];
    int R = a.R[e];
    int z, r0, c0;
    if (R == 512) {
        z = id2 >> 8;
        int yx = id2 & 255;
        r0 = (yx >> 4) * 32;
        c0 = (yx & 15) * 32;
    } else {            // Wsep: R=2048, single layer
        z = 0;
        r0 = (id2 >> 4) * 32;
        c0 = (id2 & 15) * 32;
    }
    src += (size_t)z * R * 512;
    dst += (size_t)z * a.dstride[e];
    __shared__ float t[32][33];
    int tx = threadIdx.x & 31, ty = threadIdx.x >> 5;   // 256 thr: ty 0..7
    for (int i = ty; i < 32; i += 8) t[i][tx] = src[(size_t)(r0 + i) * 512 + c0 + tx];
    __syncthreads();
    for (int i = ty; i < 32; i += 8)
        dst[(size_t)(c0 + i) * R + r0 + tx] = __float2bfloat16(t[tx][i]);
}

// ---- flat f32 -> bf16 cast ----
__global__ void cast_bf16(const float* __restrict__ src, bf16* __restrict__ dst, int n) {
    int i = blockIdx.x * blockDim.x + threadIdx.x;
    if (i < n) dst[i] = __float2bfloat16(src[i]);
}

// ---- gather qkv bias: o[l][0:512]=bq[l], [512:1024]=bk[l], [1024:1536]=bv[l] ----
__global__ void gather_qkv_bias(const float* __restrict__ bq, const float* __restrict__ bk,
                                const float* __restrict__ bv, float* __restrict__ o) {
    int idx = blockIdx.x * blockDim.x + threadIdx.x;  // L_*1536 = 6144
    if (idx >= L_ * 1536) return;
    int l = idx / 1536, j = idx - l * 1536;
    int which = j >> 9, rem = j & 511;
    const float* s = (which == 0) ? bq : (which == 1) ? bk : bv;
    o[idx] = s[l * 512 + rem];
}

// ---- positional-encoding table: pe[t][d], t < S_, d < D_ ----
__global__ void pe_kernel(float* __restrict__ pe) {
    int idx = blockIdx.x * blockDim.x + threadIdx.x;
    if (idx >= S_ * D_) return;
    int d = idx & (D_ - 1), t = idx >> 9;
    int i = d >> 1;
    float dv  = expf(-(float)(2 * i) * (9.210340371976184f / 512.0f));
    float ang = (float)t * dv;
    pe[idx] = (d & 1) ? cosf(ang) : sinf(ang);
}

// ---- embedding + PE-table add, BOTH encoders in one dispatch ----
// rows [0, NTMAIN): main (Tt=256, tokens=tokA); rows [NTMAIN, NTALL): hist
// (Tt=64, tokens=tokB). x16 is contiguous (hist block follows main block).
__global__ void embed2_kernel(const int* __restrict__ tokA,
                              const int* __restrict__ tokB,
                              const float* __restrict__ emb,
                              const float* __restrict__ pe,
                              bf16* __restrict__ x16) {
    int idx = blockIdx.x * blockDim.x + threadIdx.x;   // NTALL*128 threads
    int d4  = (idx & 127) * 4;
    int row = idx >> 7;
    int t, tok;
    if (row < NTMAIN) { t = row & (S_ - 1); tok = tokA[row]; }
    else { int r2 = row - NTMAIN; t = r2 & (T_ - 1); tok = tokB[r2]; }
    f32x4 e = *(const f32x4*)&emb[(size_t)tok * D_ + d4];
    f32x4 p = *(const f32x4*)&pe[(size_t)t * D_ + d4];
    s16x4 o;
#pragma unroll
    for (int j = 0; j < 4; ++j) o[j] = (short)f2b(e[j] + p[j]);
    *(s16x4*)&x16[(size_t)row * D_ + d4] = o;
}

// ---- single-encoder embed (fallback path only) ----
__global__ void embed_kernel(const int* __restrict__ tokens,
                             const float* __restrict__ emb,
                             const float* __restrict__ pe,
                             bf16* __restrict__ x16,
                             int Tt, int total4) {
    int idx = blockIdx.x * blockDim.x + threadIdx.x;
    if (idx >= total4) return;
    int d4  = (idx & 127) * 4;
    int row = idx >> 7;
    int t   = row & (Tt - 1);
    int tok = tokens[row];
    f32x4 e = *(const f32x4*)&emb[(size_t)tok * D_ + d4];
    f32x4 p = *(const f32x4*)&pe[(size_t)t * D_ + d4];
    s16x4 o;
#pragma unroll
    for (int j = 0; j < 4; ++j) o[j] = (short)f2b(e[j] + p[j]);
    *(s16x4*)&x16[(size_t)row * D_ + d4] = o;
}

// ---- MFMA bf16 GEMM, 128x128 tile, 4 waves, proven round-5 core ----
// lt >= 0 : qkv scatter for a single encoder (row block size 1<<lt)
// lt == -1: plain row-major C (optional addC/relu)
// lt == -2: merged qkv scatter: rows < NTMAIN -> main (lt=8), else hist (lt=6),
//           q/k/v chunks strided by QALL, hist sub-offset NTMAIN*D_.
template <typename CT>
__global__ __launch_bounds__(256) void gemm_mfma(
    const bf16* __restrict__ A, const bf16* __restrict__ Bt,
    const float* __restrict__ bias, CT* __restrict__ C,
    int M, int N, int K, int lt, int relu, int addC, int vt) {
    __shared__ short As[128 * 64];
    __shared__ short Bs[128 * 64];
    int tid  = threadIdx.x;
    int wave = tid >> 6, lane = tid & 63, lr = lane & 15, quad = lane >> 4;
    int wr = (wave >> 1) * 64, wc = (wave & 1) * 64;
    int bx = blockIdx.x, by = blockIdx.y;
    if ((gridDim.y & 7) == 0) {
        int id = by * gridDim.x + bx;
        int xcd = id & 7, slot = id >> 3;
        by = xcd + 8 * (slot / gridDim.x);
        bx = slot % gridDim.x;
    }
    int row0 = by * 128, col0 = bx * 128;
    int srow   = lane >> 3;                    // 0..7 within 8-row segment
    int gchunk = (lane & 7) ^ srow;            // XOR-swizzled source chunk
    f32x4 acc[4][4];
    f32x4 zz = {0.f, 0.f, 0.f, 0.f};
#pragma unroll
    for (int mi = 0; mi < 4; ++mi)
#pragma unroll
        for (int ni = 0; ni < 4; ++ni) acc[mi][ni] = zz;

    int lr7 = lr & 7;
    for (int kt = 0; kt < K; kt += 64) {
#pragma unroll
        for (int sseg = 0; sseg < 4; ++sseg) {
            int s = wave + sseg * 4;           // segment 0..15
            int rloc = s * 8 + srow;
            const bf16* gA = &A[(size_t)(row0 + rloc) * K + kt + gchunk * 8];
            const bf16* gB = &Bt[(size_t)(col0 + rloc) * K + kt + gchunk * 8];
            GLOAD_LDS(gA, &As[s * 512]);
            GLOAD_LDS(gB, &Bs[s * 512]);
        }
        __syncthreads();   // drains vmcnt (async LDS writes) + barrier
#pragma unroll
        for (int ks = 0; ks < 2; ++ks) {
            int cp = (((ks * 4) + quad) ^ lr7) * 8;
            short8 af[4], bf4[4];
#pragma unroll
            for (int mi = 0; mi < 4; ++mi)
                af[mi] = *(const short8*)&As[(wr + mi * 16 + lr) * 64 + cp];
#pragma unroll
            for (int ni = 0; ni < 4; ++ni)
                bf4[ni] = *(const short8*)&Bs[(wc + ni * 16 + lr) * 64 + cp];
#pragma unroll
            for (int mi = 0; mi < 4; ++mi)
#pragma unroll
                for (int ni = 0; ni < 4; ++ni)
                    acc[mi][ni] = __builtin_amdgcn_mfma_f32_16x16x32_bf16(
                        af[mi], bf4[ni], acc[mi][ni], 0, 0, 0);
        }
        __syncthreads();   // protect LDS reuse before next iteration's async writes
    }
#pragma unroll
    for (int ni = 0; ni < 4; ++ni) {
        int gc = col0 + wc + ni * 16 + lr;
        float bi = bias[gc];
#pragma unroll
        for (int mi = 0; mi < 4; ++mi) {
            int gr0 = row0 + wr + mi * 16 + quad * 4;
            f32x4 vv = acc[mi][ni];
            if (lt != -1) {
                // qkv scatter path (bf16 C only in practice)
                int ltl = (lt == -2) ? ((gr0 < NTMAIN) ? 8 : 6) : lt;
                size_t qstr = (lt == -2) ? QALL : QCHUNK;
                size_t sub  = (lt == -2 && gr0 >= NTMAIN) ? (size_t)NTMAIN * D_ : 0;
                int rb      = (lt == -2 && gr0 >= NTMAIN) ? gr0 - NTMAIN : gr0;
                int which = gc >> 9;              // 0=q,1=k,2=v (fused qkv)
                int h2 = (gc >> 7) & 3, dh = gc & 127;
                size_t base = (size_t)which * qstr + sub;
                int Tm = (1 << ltl) - 1;
                int mq = rb >> ltl, qi0 = rb & Tm;   // rb 4-aligned; qi0+3 <= Tm
                if (which == 2) {
                    // v layout: consecutive qi contiguous -> one 8B store
                    size_t oi0 = base + ((((size_t)(mq * H_ + h2)) * DH_ + dh) << ltl) + qi0;
                    s16x4 o;
#pragma unroll
                    for (int rr = 0; rr < 4; ++rr) o[rr] = (short)f2b(vv[rr] + bi);
                    *(s16x4*)((bf16*)C + oi0) = o;
                } else {
                    // q/k: 4 rows at stride DH_ from one base (offsets fold to imm)
                    bf16* dst = (bf16*)C + base +
                                ((((size_t)(mq * H_ + h2)) << ltl) + qi0) * DH_ + dh;
#pragma unroll
                    for (int rr = 0; rr < 4; ++rr)
                        dst[rr * DH_] = __float2bfloat16(vv[rr] + bi);
                }
            } else {
                CT* dst = C + (size_t)gr0 * N + gc;
#pragma unroll
                for (int rr = 0; rr < 4; ++rr) {
                    float val = vv[rr] + bi;
                    if (addC) val += toF(dst[rr * N]);
                    if (relu) val = fmaxf(val, 0.f);
                    storeF(&dst[rr * N], val);
                }
            }
        }
    }
}

// ---- MFMA flash attention: shared body, two entry points ----
struct AttnSmem {
    short Ks[64][136];
    short Vs[128][72];
    short Ps[4][16][72];
};

__device__ __forceinline__ void attn_body(
    AttnSmem& sm,
    const bf16* __restrict__ q, const bf16* __restrict__ k, const bf16* __restrict__ vt,
    bf16* __restrict__ ctx, const int* __restrict__ lens, int Tt, int nqt, int bx) {
    int qt = bx % nqt, mh = bx / nqt;
    int m = mh >> 2, h = mh & 3;
    int tid  = threadIdx.x;
    int wave = tid >> 6, lane = tid & 63, lr = lane & 15, quad = lane >> 4;
    int q0 = qt * 64;
    int kvalid = Tt;
    if (lens) { int l0 = lens[m]; kvalid = l0 < 1 ? 1 : l0; }

    short8 aq[4];
    const bf16* qrow = q + ((size_t)mh * Tt + q0 + wave * 16 + lr) * DH_;
#pragma unroll
    for (int ks2 = 0; ks2 < 4; ++ks2)
        aq[ks2] = *(const short8*)&qrow[ks2 * 32 + quad * 8];

    float mrow[4], lrow[4];
#pragma unroll
    for (int r = 0; r < 4; ++r) { mrow[r] = -INFINITY; lrow[r] = 0.f; }
    f32x4 acco[8];
    f32x4 zz = {0.f, 0.f, 0.f, 0.f};
#pragma unroll
    for (int n = 0; n < 8; ++n) acco[n] = zz;

    int nkt = Tt >> 6;
    for (int kt = 0; kt < nkt; ++kt) {
        int kb = kt * 64;
        __syncthreads();
#pragma unroll
        for (int ee = 0; ee < 4; ++ee) {
            int e = tid + ee * 256;
            int r = e >> 4, c = (e & 15) * 8;
            *(short8*)&sm.Ks[r][c] = *(const short8*)&k[((size_t)mh * Tt + kb + r) * DH_ + c];
        }
#pragma unroll
        for (int ee = 0; ee < 4; ++ee) {
            int e = tid + ee * 256;
            int r = e >> 3, c = (e & 7) * 8;
            *(short8*)&sm.Vs[r][c] = *(const short8*)&vt[((size_t)mh * DH_ + r) * Tt + kb + c];
        }
        __syncthreads();
        f32x4 s[4];
#pragma unroll
        for (int ni = 0; ni < 4; ++ni) s[ni] = zz;
#pragma unroll
        for (int ni = 0; ni < 4; ++ni)
#pragma unroll
            for (int ks2 = 0; ks2 < 4; ++ks2) {
                short8 kf = *(const short8*)&sm.Ks[ni * 16 + lr][ks2 * 32 + quad * 8];
                s[ni] = __builtin_amdgcn_mfma_f32_16x16x32_bf16(aq[ks2], kf, s[ni], 0, 0, 0);
            }
        float mx[4] = {-INFINITY, -INFINITY, -INFINITY, -INFINITY};
#pragma unroll
        for (int ni = 0; ni < 4; ++ni) {
            bool ok = (kb + ni * 16 + lr) < kvalid;
#pragma unroll
            for (int reg = 0; reg < 4; ++reg) {
                float v = s[ni][reg] * 0.08838834764831845f;
                v = ok ? v : -INFINITY;
                s[ni][reg] = v;
                mx[reg] = fmaxf(mx[reg], v);
            }
        }
#pragma unroll
        for (int d2 = 1; d2 < 16; d2 <<= 1)
#pragma unroll
            for (int reg = 0; reg < 4; ++reg)
                mx[reg] = fmaxf(mx[reg], __shfl_xor(mx[reg], d2));
        float alpha[4];
#pragma unroll
        for (int reg = 0; reg < 4; ++reg) {
            float mn = fmaxf(mrow[reg], mx[reg]);
            alpha[reg] = __expf(mrow[reg] - mn);
            mrow[reg] = mn;
        }
        float rs[4] = {0.f, 0.f, 0.f, 0.f};
#pragma unroll
        for (int ni = 0; ni < 4; ++ni)
#pragma unroll
            for (int reg = 0; reg < 4; ++reg) {
                float p = __expf(s[ni][reg] - mrow[reg]);
                s[ni][reg] = p;
                rs[reg] += p;
            }
#pragma unroll
        for (int d2 = 1; d2 < 16; d2 <<= 1)
#pragma unroll
            for (int reg = 0; reg < 4; ++reg)
                rs[reg] += __shfl_xor(rs[reg], d2);
#pragma unroll
        for (int reg = 0; reg < 4; ++reg)
            lrow[reg] = lrow[reg] * alpha[reg] + rs[reg];
#pragma unroll
        for (int ni = 0; ni < 4; ++ni)
#pragma unroll
            for (int reg = 0; reg < 4; ++reg)
                sm.Ps[wave][quad * 4 + reg][ni * 16 + lr] = (short)f2b(s[ni][reg]);
#pragma unroll
        for (int n = 0; n < 8; ++n)
#pragma unroll
            for (int reg = 0; reg < 4; ++reg) acco[n][reg] *= alpha[reg];
#pragma unroll
        for (int ks2 = 0; ks2 < 2; ++ks2) {
            short8 pf = *(const short8*)&sm.Ps[wave][lr][ks2 * 32 + quad * 8];
#pragma unroll
            for (int n = 0; n < 8; ++n) {
                short8 vf = *(const short8*)&sm.Vs[n * 16 + lr][ks2 * 32 + quad * 8];
                acco[n] = __builtin_amdgcn_mfma_f32_16x16x32_bf16(pf, vf, acco[n], 0, 0, 0);
            }
        }
    }
    float linv[4];
#pragma unroll
    for (int reg = 0; reg < 4; ++reg) linv[reg] = 1.f / lrow[reg];
#pragma unroll
    for (int n = 0; n < 8; ++n)
#pragma unroll
        for (int reg = 0; reg < 4; ++reg) {
            int qq = q0 + wave * 16 + quad * 4 + reg;
            ctx[((size_t)m * Tt + qq) * D_ + h * DH_ + n * 16 + lr] =
                __float2bfloat16(acco[n][reg] * linv[reg]);
        }
}

// standalone (split/fallback path)
__global__ __launch_bounds__(256) void fused_attn(
    const bf16* __restrict__ q, const bf16* __restrict__ k, const bf16* __restrict__ vt,
    bf16* __restrict__ ctx, const int* __restrict__ lens, int Tt, int nqt) {
    __shared__ AttnSmem sm;
    attn_body(sm, q, k, vt, ctx, lens, Tt, nqt, blockIdx.x);
}

// merged main+hist attention: blocks [0,1024) main, [1024,2560) hist
__global__ __launch_bounds__(256) void fused_attn2(
    const bf16* __restrict__ qkv, bf16* __restrict__ ctxb, const int* __restrict__ lens) {
    __shared__ AttnSmem sm;
    int bx = blockIdx.x;
    const bf16* q  = qkv;
    const bf16* k  = qkv + QALL;
    const bf16* vt = qkv + 2 * QALL;
    const int NMAINB = B_ * H_ * (S_ / 64);   // 1024
    if (bx < NMAINB) {
        attn_body(sm, q, k, vt, ctxb, nullptr, S_, S_ / 64, bx);
    } else {
        size_t off = (size_t)NTMAIN * D_;
        attn_body(sm, q + off, k + off, vt + off, ctxb + off, lens, T_, 1, bx - NMAINB);
    }
}

// ---- LayerNorm in place on bf16: 1 wave per row, short8 loads, no barriers ----
__global__ void ln_kernel(bf16* __restrict__ x,
                          const float* __restrict__ g,
                          const float* __restrict__ b) {
    int wave = threadIdx.x >> 6, lane = threadIdx.x & 63;
    size_t row = (size_t)blockIdx.x * 4 + wave;
    bf16* xr = x + row * D_ + lane * 8;
    short8 v = *(const short8*)xr;
    float f[8];
    float s = 0.f;
#pragma unroll
    for (int j = 0; j < 8; ++j) { f[j] = b2f(v[j]); s += f[j]; }
#pragma unroll
    for (int m2 = 32; m2 > 0; m2 >>= 1) s += __shfl_xor(s, m2);
    float mu = s * (1.f / 512.f);
    float qv = 0.f;
#pragma unroll
    for (int j = 0; j < 8; ++j) { f[j] -= mu; qv += f[j] * f[j]; }
#pragma unroll
    for (int m2 = 32; m2 > 0; m2 >>= 1) qv += __shfl_xor(qv, m2);
    float inv = rsqrtf(qv * (1.f / 512.f) + 1e-5f);
    f32x4 g0 = *(const f32x4*)&g[lane * 8];
    f32x4 g1 = *(const f32x4*)&g[lane * 8 + 4];
    f32x4 b0 = *(const f32x4*)&b[lane * 8];
    f32x4 b1 = *(const f32x4*)&b[lane * 8 + 4];
    short8 o;
#pragma unroll
    for (int j = 0; j < 4; ++j) o[j] = (short)f2b(f[j] * inv * g0[j] + b0[j]);
#pragma unroll
    for (int j = 0; j < 4; ++j) o[j + 4] = (short)f2b(f[j + 4] * inv * g1[j] + b1[j]);
    *(short8*)xr = o;
}

__global__ void copy_last_main(const bf16* __restrict__ x, float* __restrict__ bh) {
    int idx = blockIdx.x * blockDim.x + threadIdx.x;  // 64*512
    int b = idx >> 9, d = idx & 511;
    bh[idx] = toF(x[(size_t)(b * S_ + S_ - 1) * D_ + d]);
}

// ---- final: fused last-token add + optional relu/normalize + dot ----
__global__ void final_kernel(const float* __restrict__ sep,
                             const bf16* __restrict__ xh,
                             const int* __restrict__ lens,
                             const float* __restrict__ bh,
                             const int* __restrict__ nflag,
                             float* __restrict__ out) {
    int bn = blockIdx.x;
    int b  = bn / NH_;
    int t  = threadIdx.x;  // 256
    __shared__ float red[256];
    float v0 = sep[(size_t)bn * D_ + t];
    float v1 = sep[(size_t)bn * D_ + t + 256];
    int len = lens[bn];
    if (len > 0) {
        const bf16* xr = xh + (size_t)(bn * T_ + len - 1) * D_;
        v0 += toF(xr[t]);
        v1 += toF(xr[t + 256]);
    }
    int nf = nflag[0];
    float scale = 1.f;
    if (nf) {
        v0 = fmaxf(v0, 0.f);
        v1 = fmaxf(v1, 0.f);
        red[t] = v0 * v0 + v1 * v1;
        __syncthreads();
        for (int off = 128; off > 0; off >>= 1) {
            if (t < off) red[t] += red[t + off];
            __syncthreads();
        }
        scale = 1.f / fmaxf(sqrtf(red[0]), 1e-12f);
        __syncthreads();
    }
    red[t] = v0 * scale * bh[(size_t)b * D_ + t] + v1 * scale * bh[(size_t)b * D_ + t + 256];
    __syncthreads();
    for (int off = 128; off > 0; off >>= 1) {
        if (t < off) red[t] += red[t + off];
        __syncthreads();
    }
    if (t == 0) out[bn] = red[0];
}

extern "C" void kernel_launch(void* const* d_in, const int* in_sizes, int n_in,
                              void* d_out, int out_size, void* d_ws, size_t ws_size,
                              hipStream_t stream) {
    const int*   segment   = (const int*)d_in[0];
    const int*   prev_hist = (const int*)d_in[1];
    const int*   lens      = (const int*)d_in[2];
    const float* sep_img   = (const float*)d_in[3];
    const int*   normalize = (const int*)d_in[4];
    const float* emb       = (const float*)d_in[5];
    const float* Wq = (const float*)d_in[6];
    const float* bq = (const float*)d_in[7];
    const float* Wk = (const float*)d_in[8];
    const float* bk = (const float*)d_in[9];
    const float* Wv = (const float*)d_in[10];
    const float* bv = (const float*)d_in[11];
    const float* Wo = (const float*)d_in[12];
    const float* bo = (const float*)d_in[13];
    const float* ln1g = (const float*)d_in[14];
    const float* ln1b = (const float*)d_in[15];
    const float* W1 = (const float*)d_in[16];
    const float* b1 = (const float*)d_in[17];
    const float* W2 = (const float*)d_in[18];
    const float* b2 = (const float*)d_in[19];
    const float* ln2g = (const float*)d_in[20];
    const float* ln2b = (const float*)d_in[21];
    const float* Wsep = (const float*)d_in[22];
    const float* bsep = (const float*)d_in[23];
    float* out = (float*)d_out;

    // ---- common small buffers + weights ----
    char* w = (char*)d_ws;
    float* bh   = (float*)w; w += (size_t)B_ * D_ * 4;
    float* sepb = (float*)w; w += (size_t)B_ * NH_ * D_ * 4;
    float* bqkv = (float*)w; w += (size_t)L_ * 1536 * 4;
    float* peT  = (float*)w; w += (size_t)S_ * D_ * 4;
    bf16* Wqkvt = (bf16*)w; w += (size_t)L_ * 1536 * D_ * 2;  // [l][n=1536][k=512]
    bf16* Wot = (bf16*)w; w += (size_t)L_ * D_ * D_ * 2;
    bf16* W1t = (bf16*)w; w += (size_t)L_ * D_ * FF_ * 2;
    bf16* W2t = (bf16*)w; w += (size_t)L_ * FF_ * D_ * 2;
    bf16* Wsept = (bf16*)w; w += (size_t)IMG_ * D_ * 2;

    size_t fixed = (size_t)(w - (char*)d_ws);
    size_t needM = (size_t)NTALL * D_ * 2 * 2 + QALL * 2 * 3;
    size_t needA = (size_t)NTALL * D_ * 2 * 2 + QCHUNK * 2 * 3;
    bool merged   = (fixed + needM <= ws_size);
    bool combined = (fixed + needA <= ws_size);

    // ---- weight conversion (single dispatch) + PE table + bias gather ----
    {
        PrepArgs pa;
        pa.src[0] = Wq;   pa.dst[0] = Wqkvt;              pa.dstride[0] = (size_t)1536 * D_; pa.R[0] = 512;
        pa.src[1] = Wk;   pa.dst[1] = Wqkvt + 512 * D_;   pa.dstride[1] = (size_t)1536 * D_; pa.R[1] = 512;
        pa.src[2] = Wv;   pa.dst[2] = Wqkvt + 1024 * D_;  pa.dstride[2] = (size_t)1536 * D_; pa.R[2] = 512;
        pa.src[3] = Wo;   pa.dst[3] = Wot;                pa.dstride[3] = (size_t)D_ * D_;   pa.R[3] = 512;
        pa.src[4] = W1;   pa.dst[4] = W1t;                pa.dstride[4] = (size_t)D_ * FF_;  pa.R[4] = 512;
        pa.src[5] = W2;   pa.dst[5] = W2t;                pa.dstride[5] = (size_t)FF_ * D_;  pa.R[5] = 512;
        pa.src[6] = Wsep; pa.dst[6] = Wsept;              pa.dstride[6] = 0;                 pa.R[6] = 2048;
        prep_weights<<<7 * 1024, 256, 0, stream>>>(pa);
        gather_qkv_bias<<<(L_ * 1536 + 255) / 256, 256, 0, stream>>>(bq, bk, bv, bqkv);
        pe_kernel<<<(S_ * D_) / 256, 256, 0, stream>>>(peT);
    }

    if (merged) {
        // ---- merged layout: one qkv GEMM + one attn dispatch per layer ----
        bf16* x16  = (bf16*)w; w += (size_t)NTALL * D_ * 2;
        bf16* ctxb = (bf16*)w; w += (size_t)NTALL * D_ * 2;   // also ffmid
        bf16* qkvh = (bf16*)w; w += QALL * 2 * 3;             // q|k|v, each NTALL rows
        bf16* x16h  = x16  + (size_t)NTMAIN * D_;
        bf16* ffmid = ctxb;
        bf16* sep16 = qkvh;                                   // temp before first qkv

        // sep projection first (sep16 dead before first qkv GEMM)
        {
            int n = B_ * NH_ * IMG_;
            cast_bf16<<<(n + 255) / 256, 256, 0, stream>>>(sep_img, sep16, n);
            gemm_mfma<float><<<dim3(D_ / 128, (B_ * NH_) / 128), 256, 0, stream>>>(
                sep16, Wsept, bsep, sepb, B_ * NH_, D_, IMG_, -1, 0, 0, 0);
        }
        embed2_kernel<<<NTALL / 2, 256, 0, stream>>>(segment, prev_hist, emb, peT, x16);
        dim3 ga(D_ / 128, NTALL / 128);          // (4, 320)
        dim3 gq(1536 / 128, NTALL / 128);        // (12, 320)
        int attnBlocks = B_ * H_ * (S_ / 64) + B_ * NH_ * H_;  // 1024 + 1536
        for (int l = 0; l < L_; ++l) {
            size_t wl = (size_t)l * 1536 * D_;
            gemm_mfma<bf16><<<gq, 256, 0, stream>>>(
                x16, Wqkvt + wl, bqkv + l * 1536, qkvh, NTALL, 1536, D_, -2, 0, 0, 2);
            fused_attn2<<<attnBlocks, 256, 0, stream>>>(qkvh, ctxb, lens);
            gemm_mfma<bf16><<<ga, 256, 0, stream>>>(
                ctxb, Wot + (size_t)l * D_ * D_, bo + l * D_, x16,
                NTALL, D_, D_, -1, 0, 1, 0);  // += resid
            ln_kernel<<<NTALL / 4, 256, 0, stream>>>(x16, ln1g + l * D_, ln1b + l * D_);
            gemm_mfma<bf16><<<ga, 256, 0, stream>>>(
                x16, W1t + (size_t)l * D_ * FF_, b1 + l * FF_, ffmid,
                NTALL, FF_, D_, -1, 1, 0, 0);
            gemm_mfma<bf16><<<ga, 256, 0, stream>>>(
                ffmid, W2t + (size_t)l * FF_ * D_, b2 + l * D_, x16,
                NTALL, D_, FF_, -1, 0, 1, 0); // += resid
            ln_kernel<<<NTALL / 4, 256, 0, stream>>>(x16, ln2g + l * D_, ln2b + l * D_);
        }
        copy_last_main<<<(B_ * D_) / 256, 256, 0, stream>>>(x16, bh);
        final_kernel<<<B_ * NH_, 256, 0, stream>>>(sepb, x16h, lens, bh, normalize, out);
    } else if (combined) {
        // ---- combined layout: shared qkv chunk, 2 qkv GEMMs/layer ----
        bf16* x16  = (bf16*)w; w += (size_t)NTALL * D_ * 2;
        bf16* ctxb = (bf16*)w; w += (size_t)NTALL * D_ * 2;   // also ffmid
        bf16* qh   = (bf16*)w; w += QCHUNK * 2;               // also sep16 temp
        bf16* kh   = (bf16*)w; w += QCHUNK * 2;
        bf16* vh   = (bf16*)w; w += QCHUNK * 2;
        bf16* x16h  = x16  + (size_t)NTMAIN * D_;
        bf16* ctxh  = ctxb + (size_t)NTMAIN * D_;
        bf16* ffmid = ctxb;
        bf16* sep16 = qh;

        {
            int n = B_ * NH_ * IMG_;
            cast_bf16<<<(n + 255) / 256, 256, 0, stream>>>(sep_img, sep16, n);
            gemm_mfma<float><<<dim3(D_ / 128, (B_ * NH_) / 128), 256, 0, stream>>>(
                sep16, Wsept, bsep, sepb, B_ * NH_, D_, IMG_, -1, 0, 0, 0);
        }
        embed2_kernel<<<NTALL / 2, 256, 0, stream>>>(segment, prev_hist, emb, peT, x16);
        dim3 ga(D_ / 128, NTALL / 128);          // (4, 320)
        for (int l = 0; l < L_; ++l) {
            size_t wl = (size_t)l * 1536 * D_;
            gemm_mfma<bf16><<<dim3(12, NTMAIN / 128), 256, 0, stream>>>(
                x16, Wqkvt + wl, bqkv + l * 1536, qh, NTMAIN, 1536, D_, 8, 0, 0, 2);
            fused_attn<<<B_ * H_ * (S_ / 64), 256, 0, stream>>>(
                qh, kh, vh, ctxb, nullptr, S_, S_ / 64);
            gemm_mfma<bf16><<<dim3(12, NTHIST / 128), 256, 0, stream>>>(
                x16h, Wqkvt + wl, bqkv + l * 1536, qh, NTHIST, 1536, D_, 6, 0, 0, 2);
            fused_attn<<<B_ * NH_ * H_ * (T_ / 64), 256, 0, stream>>>(
                qh, kh, vh, ctxh, lens, T_, T_ / 64);
            gemm_mfma<bf16><<<ga, 256, 0, stream>>>(
                ctxb, Wot + (size_t)l * D_ * D_, bo + l * D_, x16,
                NTALL, D_, D_, -1, 0, 1, 0);
            ln_kernel<<<NTALL / 4, 256, 0, stream>>>(x16, ln1g + l * D_, ln1b + l * D_);
            gemm_mfma<bf16><<<ga, 256, 0, stream>>>(
                x16, W1t + (size_t)l * D_ * FF_, b1 + l * FF_, ffmid,
                NTALL, FF_, D_, -1, 1, 0, 0);
            gemm_mfma<bf16><<<ga, 256, 0, stream>>>(
                ffmid, W2t + (size_t)l * FF_ * D_, b2 + l * D_, x16,
                NTALL, D_, FF_, -1, 0, 1, 0);
            ln_kernel<<<NTALL / 4, 256, 0, stream>>>(x16, ln2g + l * D_, ln2b + l * D_);
        }
        copy_last_main<<<(B_ * D_) / 256, 256, 0, stream>>>(x16, bh);
        final_kernel<<<B_ * NH_, 256, 0, stream>>>(sepb, x16h, lens, bh, normalize, out);
    } else {
        // ---- fallback: split layout/behavior ----
        bf16* x16  = (bf16*)w; w += QCHUNK * 2;
        bf16* ctxb = (bf16*)w; w += QCHUNK * 2;
        bf16* qh   = (bf16*)w; w += QCHUNK * 2;
        bf16* kh   = (bf16*)w; w += QCHUNK * 2;
        bf16* vh   = (bf16*)w; w += QCHUNK * 2;
        bf16* sep16 = (bf16*)w; w += (size_t)B_ * NH_ * IMG_ * 2;
        bf16* ffmid = qh;

        {
            int n = B_ * NH_ * IMG_;
            cast_bf16<<<(n + 255) / 256, 256, 0, stream>>>(sep_img, sep16, n);
        }
        auto run_encoder = [&](int M, int Tt, int lt, const int* lens_p) {
            int NT = M * Tt;
            dim3 gg(D_ / 128, NT / 128);
            dim3 gq(1536 / 128, NT / 128);
            int nqt = Tt / 64;
            for (int l = 0; l < L_; ++l) {
                gemm_mfma<bf16><<<gq, 256, 0, stream>>>(
                    x16, Wqkvt + (size_t)l * 1536 * D_, bqkv + l * 1536, qh,
                    NT, 1536, D_, lt, 0, 0, 2);
                fused_attn<<<M * H_ * nqt, 256, 0, stream>>>(
                    qh, kh, vh, ctxb, lens_p, Tt, nqt);
                gemm_mfma<bf16><<<gg, 256, 0, stream>>>(
                    ctxb, Wot + (size_t)l * D_ * D_, bo + l * D_, x16,
                    NT, D_, D_, -1, 0, 1, 0);
                ln_kernel<<<NT / 4, 256, 0, stream>>>(x16, ln1g + l * D_, ln1b + l * D_);
                gemm_mfma<bf16><<<gg, 256, 0, stream>>>(
                    x16, W1t + (size_t)l * D_ * FF_, b1 + l * FF_, ffmid,
                    NT, FF_, D_, -1, 1, 0, 0);
                gemm_mfma<bf16><<<gg, 256, 0, stream>>>(
                    ffmid, W2t + (size_t)l * FF_ * D_, b2 + l * D_, x16,
                    NT, D_, FF_, -1, 0, 1, 0);
                ln_kernel<<<NT / 4, 256, 0, stream>>>(x16, ln2g + l * D_, ln2b + l * D_);
            }
        };
        embed_kernel<<<(NTMAIN * D_ / 4) / 256, 256, 0, stream>>>(
            segment, emb, peT, x16, S_, NTMAIN * D_ / 4);
        run_encoder(B_, S_, 8, nullptr);
        copy_last_main<<<(B_ * D_) / 256, 256, 0, stream>>>(x16, bh);
        gemm_mfma<float><<<dim3(D_ / 128, (B_ * NH_) / 128), 256, 0, stream>>>(
            sep16, Wsept, bsep, sepb, B_ * NH_, D_, IMG_, -1, 0, 0, 0);
        embed_kernel<<<(NTHIST * D_ / 4) / 256, 256, 0, stream>>>(
            prev_hist, emb, peT, x16, T_, NTHIST * D_ / 4);
        run_encoder(B_ * NH_, T_, 6, lens);
        final_kernel<<<B_ * NH_, 256, 0, stream>>>(sepb, x16, lens, bh, normalize, out);
    }
}

// Round 9
// 1393.440 us; speedup vs baseline: 1.3291x; 1.1577x over previous
//
#include <hip/hip_runtime.h>
#include <hip/hip_bf16.h>
#include <math.h>

typedef __hip_bfloat16 bf16;
typedef __attribute__((ext_vector_type(8))) short short8;
typedef __attribute__((ext_vector_type(4))) short s16x4;
typedef __attribute__((ext_vector_type(4))) float f32x4;

#define D_    512
#define H_    4
#define DH_   128
#define L_    4
#define FF_   512
#define B_    64
#define NH_   6
#define S_    256
#define T_    64
#define IMG_  2048
#define NTMAIN (B_ * S_)              // 16384
#define NTHIST (B_ * NH_ * T_)        // 24576
#define NTALL  (NTMAIN + NTHIST)      // 40960
#define QCHUNK ((size_t)NTHIST * D_)  // element stride between q,k,v buffers (split path)
#define QALL   ((size_t)NTALL * D_)   // element stride between q,k,v buffers (merged path)

// async global->LDS, 16B per lane, LDS dest = wave-uniform base + lane*16
#define GLOAD_LDS(gp, lp) __builtin_amdgcn_global_load_lds( \
    (const __attribute__((address_space(1))) void*)(gp),    \
    (__attribute__((address_space(3))) void*)(lp), 16, 0, 0)

__device__ __forceinline__ float toF(bf16 v)  { return __bfloat162float(v); }
__device__ __forceinline__ float toF(float v) { return v; }
__device__ __forceinline__ void storeF(bf16* p, float v)  { *p = __float2bfloat16(v); }
__device__ __forceinline__ void storeF(float* p, float v) { *p = v; }

// round-to-nearest-even f32 -> bf16 bits
__device__ __forceinline__ unsigned short f2b(float f) {
    unsigned u = __float_as_uint(f);
    unsigned r = (u + 0x7fffu + ((u >> 16) & 1u)) >> 16;
    return (unsigned short)r;
}
// bf16 bits -> f32 (exact)
__device__ __forceinline__ float b2f(short b) {
    return __uint_as_float(((unsigned)(unsigned short)b) << 16);
}

// ---- merged weight transpose + cast: 7 weight tensors in ONE dispatch ----
struct PrepArgs {
    const float* src[7];
    bf16*        dst[7];
    size_t       dstride[7];
    int          R[7];        // 512 (z=4) or 2048 (z=1)
};
__global__ void prep_weights(PrepArgs a) {
    int e   = blockIdx.x >> 10;
    int id2 = blockIdx.x & 1023;
    const float* src = a.src[e];
    bf16* dst = a.dst[e];
    int R = a.R[e];
    int z, r0, c0;
    if (R == 512) {
        z = id2 >> 8;
        int yx = id2 & 255;
        r0 = (yx >> 4) * 32;
        c0 = (yx & 15) * 32;
    } else {            // Wsep: R=2048, single layer
        z = 0;
        r0 = (id2 >> 4) * 32;
        c0 = (id2 & 15) * 32;
    }
    src += (size_t)z * R * 512;
    dst += (size_t)z * a.dstride[e];
    __shared__ float t[32][33];
    int tx = threadIdx.x & 31, ty = threadIdx.x >> 5;   // 256 thr: ty 0..7
    for (int i = ty; i < 32; i += 8) t[i][tx] = src[(size_t)(r0 + i) * 512 + c0 + tx];
    __syncthreads();
    for (int i = ty; i < 32; i += 8)
        dst[(size_t)(c0 + i) * R + r0 + tx] = __float2bfloat16(t[tx][i]);
}

// ---- flat f32 -> bf16 cast ----
__global__ void cast_bf16(const float* __restrict__ src, bf16* __restrict__ dst, int n) {
    int i = blockIdx.x * blockDim.x + threadIdx.x;
    if (i < n) dst[i] = __float2bfloat16(src[i]);
}

// ---- gather qkv bias: o[l][0:512]=bq[l], [512:1024]=bk[l], [1024:1536]=bv[l] ----
__global__ void gather_qkv_bias(const float* __restrict__ bq, const float* __restrict__ bk,
                                const float* __restrict__ bv, float* __restrict__ o) {
    int idx = blockIdx.x * blockDim.x + threadIdx.x;  // L_*1536 = 6144
    if (idx >= L_ * 1536) return;
    int l = idx / 1536, j = idx - l * 1536;
    int which = j >> 9, rem = j & 511;
    const float* s = (which == 0) ? bq : (which == 1) ? bk : bv;
    o[idx] = s[l * 512 + rem];
}

// ---- positional-encoding table: pe[t][d], t < S_, d < D_ ----
__global__ void pe_kernel(float* __restrict__ pe) {
    int idx = blockIdx.x * blockDim.x + threadIdx.x;
    if (idx >= S_ * D_) return;
    int d = idx & (D_ - 1), t = idx >> 9;
    int i = d >> 1;
    float dv  = expf(-(float)(2 * i) * (9.210340371976184f / 512.0f));
    float ang = (float)t * dv;
    pe[idx] = (d & 1) ? cosf(ang) : sinf(ang);
}

// ---- embedding + PE-table add, BOTH encoders in one dispatch ----
__global__ void embed2_kernel(const int* __restrict__ tokA,
                              const int* __restrict__ tokB,
                              const float* __restrict__ emb,
                              const float* __restrict__ pe,
                              bf16* __restrict__ x16) {
    int idx = blockIdx.x * blockDim.x + threadIdx.x;   // NTALL*128 threads
    int d4  = (idx & 127) * 4;
    int row = idx >> 7;
    int t, tok;
    if (row < NTMAIN) { t = row & (S_ - 1); tok = tokA[row]; }
    else { int r2 = row - NTMAIN; t = r2 & (T_ - 1); tok = tokB[r2]; }
    f32x4 e = *(const f32x4*)&emb[(size_t)tok * D_ + d4];
    f32x4 p = *(const f32x4*)&pe[(size_t)t * D_ + d4];
    s16x4 o;
#pragma unroll
    for (int j = 0; j < 4; ++j) o[j] = (short)f2b(e[j] + p[j]);
    *(s16x4*)&x16[(size_t)row * D_ + d4] = o;
}

// ---- single-encoder embed (fallback path only) ----
__global__ void embed_kernel(const int* __restrict__ tokens,
                             const float* __restrict__ emb,
                             const float* __restrict__ pe,
                             bf16* __restrict__ x16,
                             int Tt, int total4) {
    int idx = blockIdx.x * blockDim.x + threadIdx.x;
    if (idx >= total4) return;
    int d4  = (idx & 127) * 4;
    int row = idx >> 7;
    int t   = row & (Tt - 1);
    int tok = tokens[row];
    f32x4 e = *(const f32x4*)&emb[(size_t)tok * D_ + d4];
    f32x4 p = *(const f32x4*)&pe[(size_t)t * D_ + d4];
    s16x4 o;
#pragma unroll
    for (int j = 0; j < 4; ++j) o[j] = (short)f2b(e[j] + p[j]);
    *(s16x4*)&x16[(size_t)row * D_ + d4] = o;
}

// ---- MFMA bf16 GEMM, 128x128 tile, 4 waves (qkv scatter paths) ----
// lt >= 0 : qkv scatter for a single encoder (row block size 1<<lt)
// lt == -1: plain row-major C (optional addC/relu)
// lt == -2: merged qkv scatter: rows < NTMAIN -> main (lt=8), else hist (lt=6)
template <typename CT>
__global__ __launch_bounds__(256) void gemm_mfma(
    const bf16* __restrict__ A, const bf16* __restrict__ Bt,
    const float* __restrict__ bias, CT* __restrict__ C,
    int M, int N, int K, int lt, int relu, int addC, int vt) {
    __shared__ short As[128 * 64];
    __shared__ short Bs[128 * 64];
    int tid  = threadIdx.x;
    int wave = tid >> 6, lane = tid & 63, lr = lane & 15, quad = lane >> 4;
    int wr = (wave >> 1) * 64, wc = (wave & 1) * 64;
    int bx = blockIdx.x, by = blockIdx.y;
    if ((gridDim.y & 7) == 0) {
        int id = by * gridDim.x + bx;
        int xcd = id & 7, slot = id >> 3;
        by = xcd + 8 * (slot / gridDim.x);
        bx = slot % gridDim.x;
    }
    int row0 = by * 128, col0 = bx * 128;
    int srow   = lane >> 3;                    // 0..7 within 8-row segment
    int gchunk = (lane & 7) ^ srow;            // XOR-swizzled source chunk
    f32x4 acc[4][4];
    f32x4 zz = {0.f, 0.f, 0.f, 0.f};
#pragma unroll
    for (int mi = 0; mi < 4; ++mi)
#pragma unroll
        for (int ni = 0; ni < 4; ++ni) acc[mi][ni] = zz;

    int lr7 = lr & 7;
    for (int kt = 0; kt < K; kt += 64) {
#pragma unroll
        for (int sseg = 0; sseg < 4; ++sseg) {
            int s = wave + sseg * 4;           // segment 0..15
            int rloc = s * 8 + srow;
            const bf16* gA = &A[(size_t)(row0 + rloc) * K + kt + gchunk * 8];
            const bf16* gB = &Bt[(size_t)(col0 + rloc) * K + kt + gchunk * 8];
            GLOAD_LDS(gA, &As[s * 512]);
            GLOAD_LDS(gB, &Bs[s * 512]);
        }
        __syncthreads();   // drains vmcnt (async LDS writes) + barrier
#pragma unroll
        for (int ks = 0; ks < 2; ++ks) {
            int cp = (((ks * 4) + quad) ^ lr7) * 8;
            short8 af[4], bf4[4];
#pragma unroll
            for (int mi = 0; mi < 4; ++mi)
                af[mi] = *(const short8*)&As[(wr + mi * 16 + lr) * 64 + cp];
#pragma unroll
            for (int ni = 0; ni < 4; ++ni)
                bf4[ni] = *(const short8*)&Bs[(wc + ni * 16 + lr) * 64 + cp];
#pragma unroll
            for (int mi = 0; mi < 4; ++mi)
#pragma unroll
                for (int ni = 0; ni < 4; ++ni)
                    acc[mi][ni] = __builtin_amdgcn_mfma_f32_16x16x32_bf16(
                        af[mi], bf4[ni], acc[mi][ni], 0, 0, 0);
        }
        __syncthreads();   // protect LDS reuse before next iteration's async writes
    }
#pragma unroll
    for (int ni = 0; ni < 4; ++ni) {
        int gc = col0 + wc + ni * 16 + lr;
        float bi = bias[gc];
#pragma unroll
        for (int mi = 0; mi < 4; ++mi) {
            int gr0 = row0 + wr + mi * 16 + quad * 4;
            f32x4 vv = acc[mi][ni];
            if (lt != -1) {
                // qkv scatter path (bf16 C only in practice)
                int ltl = (lt == -2) ? ((gr0 < NTMAIN) ? 8 : 6) : lt;
                size_t qstr = (lt == -2) ? QALL : QCHUNK;
                size_t sub  = (lt == -2 && gr0 >= NTMAIN) ? (size_t)NTMAIN * D_ : 0;
                int rb      = (lt == -2 && gr0 >= NTMAIN) ? gr0 - NTMAIN : gr0;
                int which = gc >> 9;              // 0=q,1=k,2=v (fused qkv)
                int h2 = (gc >> 7) & 3, dh = gc & 127;
                size_t base = (size_t)which * qstr + sub;
                int Tm = (1 << ltl) - 1;
                int mq = rb >> ltl, qi0 = rb & Tm;   // rb 4-aligned; qi0+3 <= Tm
                if (which == 2) {
                    // v layout: consecutive qi contiguous -> one 8B store
                    size_t oi0 = base + ((((size_t)(mq * H_ + h2)) * DH_ + dh) << ltl) + qi0;
                    s16x4 o;
#pragma unroll
                    for (int rr = 0; rr < 4; ++rr) o[rr] = (short)f2b(vv[rr] + bi);
                    *(s16x4*)((bf16*)C + oi0) = o;
                } else {
                    // q/k: 4 rows at stride DH_ from one base (offsets fold to imm)
                    bf16* dst = (bf16*)C + base +
                                ((((size_t)(mq * H_ + h2)) << ltl) + qi0) * DH_ + dh;
#pragma unroll
                    for (int rr = 0; rr < 4; ++rr)
                        dst[rr * DH_] = __float2bfloat16(vv[rr] + bi);
                }
            } else {
                CT* dst = C + (size_t)gr0 * N + gc;
#pragma unroll
                for (int rr = 0; rr < 4; ++rr) {
                    float val = vv[rr] + bi;
                    if (addC) val += toF(dst[rr * N]);
                    if (relu) val = fmaxf(val, 0.f);
                    storeF(&dst[rr * N], val);
                }
            }
        }
    }
}

// ---- MFMA bf16 GEMM, 64x128 tile, 4 waves (plain/addC/relu paths) ----
// Same K-order per output element as the 128-tile kernel -> bit-identical.
// 2x the blocks for the latency-bound N=512 GEMMs; 24 KB LDS.
template <typename CT>
__global__ __launch_bounds__(256) void gemm_mfma64(
    const bf16* __restrict__ A, const bf16* __restrict__ Bt,
    const float* __restrict__ bias, CT* __restrict__ C,
    int M, int N, int K, int relu, int addC) {
    __shared__ short As[64 * 64];    // 8 KB
    __shared__ short Bs[128 * 64];   // 16 KB
    int tid  = threadIdx.x;
    int wave = tid >> 6, lane = tid & 63, lr = lane & 15, quad = lane >> 4;
    int wr = (wave >> 1) * 32, wc = (wave & 1) * 64;   // per-wave 32x64 output
    int bx = blockIdx.x, by = blockIdx.y;
    if ((gridDim.y & 7) == 0) {
        int id = by * gridDim.x + bx;
        int xcd = id & 7, slot = id >> 3;
        by = xcd + 8 * (slot / gridDim.x);
        bx = slot % gridDim.x;
    }
    int row0 = by * 64, col0 = bx * 128;
    int srow   = lane >> 3;
    int gchunk = (lane & 7) ^ srow;            // XOR-swizzled source chunk
    f32x4 acc[2][4];
    f32x4 zz = {0.f, 0.f, 0.f, 0.f};
#pragma unroll
    for (int mi = 0; mi < 2; ++mi)
#pragma unroll
        for (int ni = 0; ni < 4; ++ni) acc[mi][ni] = zz;

    int lr7 = lr & 7;
    for (int kt = 0; kt < K; kt += 64) {
#pragma unroll
        for (int j = 0; j < 2; ++j) {          // A: 8 segs, wave stages 2
            int s = wave * 2 + j;
            int rloc = s * 8 + srow;
            GLOAD_LDS(&A[(size_t)(row0 + rloc) * K + kt + gchunk * 8], &As[s * 512]);
        }
#pragma unroll
        for (int sseg = 0; sseg < 4; ++sseg) { // B: 16 segs, wave stages 4
            int s = wave + sseg * 4;
            int rloc = s * 8 + srow;
            GLOAD_LDS(&Bt[(size_t)(col0 + rloc) * K + kt + gchunk * 8], &Bs[s * 512]);
        }
        __syncthreads();
#pragma unroll
        for (int ks = 0; ks < 2; ++ks) {
            int cp = (((ks * 4) + quad) ^ lr7) * 8;
            short8 af[2], bf4[4];
#pragma unroll
            for (int mi = 0; mi < 2; ++mi)
                af[mi] = *(const short8*)&As[(wr + mi * 16 + lr) * 64 + cp];
#pragma unroll
            for (int ni = 0; ni < 4; ++ni)
                bf4[ni] = *(const short8*)&Bs[(wc + ni * 16 + lr) * 64 + cp];
#pragma unroll
            for (int mi = 0; mi < 2; ++mi)
#pragma unroll
                for (int ni = 0; ni < 4; ++ni)
                    acc[mi][ni] = __builtin_amdgcn_mfma_f32_16x16x32_bf16(
                        af[mi], bf4[ni], acc[mi][ni], 0, 0, 0);
        }
        __syncthreads();
    }
#pragma unroll
    for (int ni = 0; ni < 4; ++ni) {
        int gc = col0 + wc + ni * 16 + lr;
        float bi = bias[gc];
#pragma unroll
        for (int mi = 0; mi < 2; ++mi) {
            int gr0 = row0 + wr + mi * 16 + quad * 4;
            f32x4 vv = acc[mi][ni];
            CT* dst = C + (size_t)gr0 * N + gc;
#pragma unroll
            for (int rr = 0; rr < 4; ++rr) {
                float val = vv[rr] + bi;
                if (addC) val += toF(dst[rr * N]);
                if (relu) val = fmaxf(val, 0.f);
                storeF(&dst[rr * N], val);
            }
        }
    }
}

// ---- MFMA flash attention: shared body, two entry points ----
struct AttnSmem {
    short Ks[64][136];
    short Vs[128][72];
    short Ps[4][16][72];
};

__device__ __forceinline__ void attn_body(
    AttnSmem& sm,
    const bf16* __restrict__ q, const bf16* __restrict__ k, const bf16* __restrict__ vt,
    bf16* __restrict__ ctx, const int* __restrict__ lens, int Tt, int nqt, int bx) {
    int qt = bx % nqt, mh = bx / nqt;
    int m = mh >> 2, h = mh & 3;
    int tid  = threadIdx.x;
    int wave = tid >> 6, lane = tid & 63, lr = lane & 15, quad = lane >> 4;
    int q0 = qt * 64;
    int kvalid = Tt;
    if (lens) { int l0 = lens[m]; kvalid = l0 < 1 ? 1 : l0; }

    short8 aq[4];
    const bf16* qrow = q + ((size_t)mh * Tt + q0 + wave * 16 + lr) * DH_;
#pragma unroll
    for (int ks2 = 0; ks2 < 4; ++ks2)
        aq[ks2] = *(const short8*)&qrow[ks2 * 32 + quad * 8];

    float mrow[4], lrow[4];
#pragma unroll
    for (int r = 0; r < 4; ++r) { mrow[r] = -INFINITY; lrow[r] = 0.f; }
    f32x4 acco[8];
    f32x4 zz = {0.f, 0.f, 0.f, 0.f};
#pragma unroll
    for (int n = 0; n < 8; ++n) acco[n] = zz;

    int nkt = Tt >> 6;
    for (int kt = 0; kt < nkt; ++kt) {
        int kb = kt * 64;
        __syncthreads();
#pragma unroll
        for (int ee = 0; ee < 4; ++ee) {
            int e = tid + ee * 256;
            int r = e >> 4, c = (e & 15) * 8;
            *(short8*)&sm.Ks[r][c] = *(const short8*)&k[((size_t)mh * Tt + kb + r) * DH_ + c];
        }
#pragma unroll
        for (int ee = 0; ee < 4; ++ee) {
            int e = tid + ee * 256;
            int r = e >> 3, c = (e & 7) * 8;
            *(short8*)&sm.Vs[r][c] = *(const short8*)&vt[((size_t)mh * DH_ + r) * Tt + kb + c];
        }
        __syncthreads();
        f32x4 s[4];
#pragma unroll
        for (int ni = 0; ni < 4; ++ni) s[ni] = zz;
        __builtin_amdgcn_s_setprio(1);
#pragma unroll
        for (int ni = 0; ni < 4; ++ni)
#pragma unroll
            for (int ks2 = 0; ks2 < 4; ++ks2) {
                short8 kf = *(const short8*)&sm.Ks[ni * 16 + lr][ks2 * 32 + quad * 8];
                s[ni] = __builtin_amdgcn_mfma_f32_16x16x32_bf16(aq[ks2], kf, s[ni], 0, 0, 0);
            }
        __builtin_amdgcn_s_setprio(0);
        float mx[4] = {-INFINITY, -INFINITY, -INFINITY, -INFINITY};
#pragma unroll
        for (int ni = 0; ni < 4; ++ni) {
            bool ok = (kb + ni * 16 + lr) < kvalid;
#pragma unroll
            for (int reg = 0; reg < 4; ++reg) {
                float v = s[ni][reg] * 0.08838834764831845f;
                v = ok ? v : -INFINITY;
                s[ni][reg] = v;
                mx[reg] = fmaxf(mx[reg], v);
            }
        }
#pragma unroll
        for (int d2 = 1; d2 < 16; d2 <<= 1)
#pragma unroll
            for (int reg = 0; reg < 4; ++reg)
                mx[reg] = fmaxf(mx[reg], __shfl_xor(mx[reg], d2));
        float alpha[4];
#pragma unroll
        for (int reg = 0; reg < 4; ++reg) {
            float mn = fmaxf(mrow[reg], mx[reg]);
            alpha[reg] = __expf(mrow[reg] - mn);
            mrow[reg] = mn;
        }
        float rs[4] = {0.f, 0.f, 0.f, 0.f};
#pragma unroll
        for (int ni = 0; ni < 4; ++ni)
#pragma unroll
            for (int reg = 0; reg < 4; ++reg) {
                float p = __expf(s[ni][reg] - mrow[reg]);
                s[ni][reg] = p;
                rs[reg] += p;
            }
#pragma unroll
        for (int d2 = 1; d2 < 16; d2 <<= 1)
#pragma unroll
            for (int reg = 0; reg < 4; ++reg)
                rs[reg] += __shfl_xor(rs[reg], d2);
#pragma unroll
        for (int reg = 0; reg < 4; ++reg)
            lrow[reg] = lrow[reg] * alpha[reg] + rs[reg];
#pragma unroll
        for (int ni = 0; ni < 4; ++ni)
#pragma unroll
            for (int reg = 0; reg < 4; ++reg)
                sm.Ps[wave][quad * 4 + reg][ni * 16 + lr] = (short)f2b(s[ni][reg]);
#pragma unroll
        for (int n = 0; n < 8; ++n)
#pragma unroll
            for (int reg = 0; reg < 4; ++reg) acco[n][reg] *= alpha[reg];
        __builtin_amdgcn_s_setprio(1);
#pragma unroll
        for (int ks2 = 0; ks2 < 2; ++ks2) {
            short8 pf = *(const short8*)&sm.Ps[wave][lr][ks2 * 32 + quad * 8];
#pragma unroll
            for (int n = 0; n < 8; ++n) {
                short8 vf = *(const short8*)&sm.Vs[n * 16 + lr][ks2 * 32 + quad * 8];
                acco[n] = __builtin_amdgcn_mfma_f32_16x16x32_bf16(pf, vf, acco[n], 0, 0, 0);
            }
        }
        __builtin_amdgcn_s_setprio(0);
    }
    float linv[4];
#pragma unroll
    for (int reg = 0; reg < 4; ++reg) linv[reg] = 1.f / lrow[reg];
#pragma unroll
    for (int n = 0; n < 8; ++n)
#pragma unroll
        for (int reg = 0; reg < 4; ++reg) {
            int qq = q0 + wave * 16 + quad * 4 + reg;
            ctx[((size_t)m * Tt + qq) * D_ + h * DH_ + n * 16 + lr] =
                __float2bfloat16(acco[n][reg] * linv[reg]);
        }
}

// standalone (split/fallback path)
__global__ __launch_bounds__(256) void fused_attn(
    const bf16* __restrict__ q, const bf16* __restrict__ k, const bf16* __restrict__ vt,
    bf16* __restrict__ ctx, const int* __restrict__ lens, int Tt, int nqt) {
    __shared__ AttnSmem sm;
    attn_body(sm, q, k, vt, ctx, lens, Tt, nqt, blockIdx.x);
}

// merged main+hist attention: blocks [0,1024) main, [1024,2560) hist
__global__ __launch_bounds__(256) void fused_attn2(
    const bf16* __restrict__ qkv, bf16* __restrict__ ctxb, const int* __restrict__ lens) {
    __shared__ AttnSmem sm;
    int bx = blockIdx.x;
    const bf16* q  = qkv;
    const bf16* k  = qkv + QALL;
    const bf16* vt = qkv + 2 * QALL;
    const int NMAINB = B_ * H_ * (S_ / 64);   // 1024
    if (bx < NMAINB) {
        attn_body(sm, q, k, vt, ctxb, nullptr, S_, S_ / 64, bx);
    } else {
        size_t off = (size_t)NTMAIN * D_;
        attn_body(sm, q + off, k + off, vt + off, ctxb + off, lens, T_, 1, bx - NMAINB);
    }
}

// ---- LayerNorm in place on bf16: 1 wave per row, short8 loads, no barriers ----
__global__ void ln_kernel(bf16* __restrict__ x,
                          const float* __restrict__ g,
                          const float* __restrict__ b) {
    int wave = threadIdx.x >> 6, lane = threadIdx.x & 63;
    size_t row = (size_t)blockIdx.x * 4 + wave;
    bf16* xr = x + row * D_ + lane * 8;
    short8 v = *(const short8*)xr;
    float f[8];
    float s = 0.f;
#pragma unroll
    for (int j = 0; j < 8; ++j) { f[j] = b2f(v[j]); s += f[j]; }
#pragma unroll
    for (int m2 = 32; m2 > 0; m2 >>= 1) s += __shfl_xor(s, m2);
    float mu = s * (1.f / 512.f);
    float qv = 0.f;
#pragma unroll
    for (int j = 0; j < 8; ++j) { f[j] -= mu; qv += f[j] * f[j]; }
#pragma unroll
    for (int m2 = 32; m2 > 0; m2 >>= 1) qv += __shfl_xor(qv, m2);
    float inv = rsqrtf(qv * (1.f / 512.f) + 1e-5f);
    f32x4 g0 = *(const f32x4*)&g[lane * 8];
    f32x4 g1 = *(const f32x4*)&g[lane * 8 + 4];
    f32x4 b0 = *(const f32x4*)&b[lane * 8];
    f32x4 b1 = *(const f32x4*)&b[lane * 8 + 4];
    short8 o;
#pragma unroll
    for (int j = 0; j < 4; ++j) o[j] = (short)f2b(f[j] * inv * g0[j] + b0[j]);
#pragma unroll
    for (int j = 0; j < 4; ++j) o[j + 4] = (short)f2b(f[j + 4] * inv * g1[j] + b1[j]);
    *(short8*)xr = o;
}

__global__ void copy_last_main(const bf16* __restrict__ x, float* __restrict__ bh) {
    int idx = blockIdx.x * blockDim.x + threadIdx.x;  // 64*512
    int b = idx >> 9, d = idx & 511;
    bh[idx] = toF(x[(size_t)(b * S_ + S_ - 1) * D_ + d]);
}

// ---- final: fused last-token add + optional relu/normalize + dot ----
__global__ void final_kernel(const float* __restrict__ sep,
                             const bf16* __restrict__ xh,
                             const int* __restrict__ lens,
                             const float* __restrict__ bh,
                             const int* __restrict__ nflag,
                             float* __restrict__ out) {
    int bn = blockIdx.x;
    int b  = bn / NH_;
    int t  = threadIdx.x;  // 256
    __shared__ float red[256];
    float v0 = sep[(size_t)bn * D_ + t];
    float v1 = sep[(size_t)bn * D_ + t + 256];
    int len = lens[bn];
    if (len > 0) {
        const bf16* xr = xh + (size_t)(bn * T_ + len - 1) * D_;
        v0 += toF(xr[t]);
        v1 += toF(xr[t + 256]);
    }
    int nf = nflag[0];
    float scale = 1.f;
    if (nf) {
        v0 = fmaxf(v0, 0.f);
        v1 = fmaxf(v1, 0.f);
        red[t] = v0 * v0 + v1 * v1;
        __syncthreads();
        for (int off = 128; off > 0; off >>= 1) {
            if (t < off) red[t] += red[t + off];
            __syncthreads();
        }
        scale = 1.f / fmaxf(sqrtf(red[0]), 1e-12f);
        __syncthreads();
    }
    red[t] = v0 * scale * bh[(size_t)b * D_ + t] + v1 * scale * bh[(size_t)b * D_ + t + 256];
    __syncthreads();
    for (int off = 128; off > 0; off >>= 1) {
        if (t < off) red[t] += red[t + off];
        __syncthreads();
    }
    if (t == 0) out[bn] = red[0];
}

extern "C" void kernel_launch(void* const* d_in, const int* in_sizes, int n_in,
                              void* d_out, int out_size, void* d_ws, size_t ws_size,
                              hipStream_t stream) {
    const int*   segment   = (const int*)d_in[0];
    const int*   prev_hist = (const int*)d_in[1];
    const int*   lens      = (const int*)d_in[2];
    const float* sep_img   = (const float*)d_in[3];
    const int*   normalize = (const int*)d_in[4];
    const float* emb       = (const float*)d_in[5];
    const float* Wq = (const float*)d_in[6];
    const float* bq = (const float*)d_in[7];
    const float* Wk = (const float*)d_in[8];
    const float* bk = (const float*)d_in[9];
    const float* Wv = (const float*)d_in[10];
    const float* bv = (const float*)d_in[11];
    const float* Wo = (const float*)d_in[12];
    const float* bo = (const float*)d_in[13];
    const float* ln1g = (const float*)d_in[14];
    const float* ln1b = (const float*)d_in[15];
    const float* W1 = (const float*)d_in[16];
    const float* b1 = (const float*)d_in[17];
    const float* W2 = (const float*)d_in[18];
    const float* b2 = (const float*)d_in[19];
    const float* ln2g = (const float*)d_in[20];
    const float* ln2b = (const float*)d_in[21];
    const float* Wsep = (const float*)d_in[22];
    const float* bsep = (const float*)d_in[23];
    float* out = (float*)d_out;

    // ---- common small buffers + weights ----
    char* w = (char*)d_ws;
    float* bh   = (float*)w; w += (size_t)B_ * D_ * 4;
    float* sepb = (float*)w; w += (size_t)B_ * NH_ * D_ * 4;
    float* bqkv = (float*)w; w += (size_t)L_ * 1536 * 4;
    float* peT  = (float*)w; w += (size_t)S_ * D_ * 4;
    bf16* Wqkvt = (bf16*)w; w += (size_t)L_ * 1536 * D_ * 2;  // [l][n=1536][k=512]
    bf16* Wot = (bf16*)w; w += (size_t)L_ * D_ * D_ * 2;
    bf16* W1t = (bf16*)w; w += (size_t)L_ * D_ * FF_ * 2;
    bf16* W2t = (bf16*)w; w += (size_t)L_ * FF_ * D_ * 2;
    bf16* Wsept = (bf16*)w; w += (size_t)IMG_ * D_ * 2;

    size_t fixed = (size_t)(w - (char*)d_ws);
    size_t needM = (size_t)NTALL * D_ * 2 * 2 + QALL * 2 * 3;
    size_t needA = (size_t)NTALL * D_ * 2 * 2 + QCHUNK * 2 * 3;
    bool merged   = (fixed + needM <= ws_size);
    bool combined = (fixed + needA <= ws_size);

    // ---- weight conversion (single dispatch) + PE table + bias gather ----
    {
        PrepArgs pa;
        pa.src[0] = Wq;   pa.dst[0] = Wqkvt;              pa.dstride[0] = (size_t)1536 * D_; pa.R[0] = 512;
        pa.src[1] = Wk;   pa.dst[1] = Wqkvt + 512 * D_;   pa.dstride[1] = (size_t)1536 * D_; pa.R[1] = 512;
        pa.src[2] = Wv;   pa.dst[2] = Wqkvt + 1024 * D_;  pa.dstride[2] = (size_t)1536 * D_; pa.R[2] = 512;
        pa.src[3] = Wo;   pa.dst[3] = Wot;                pa.dstride[3] = (size_t)D_ * D_;   pa.R[3] = 512;
        pa.src[4] = W1;   pa.dst[4] = W1t;                pa.dstride[4] = (size_t)D_ * FF_;  pa.R[4] = 512;
        pa.src[5] = W2;   pa.dst[5] = W2t;                pa.dstride[5] = (size_t)FF_ * D_;  pa.R[5] = 512;
        pa.src[6] = Wsep; pa.dst[6] = Wsept;              pa.dstride[6] = 0;                 pa.R[6] = 2048;
        prep_weights<<<7 * 1024, 256, 0, stream>>>(pa);
        gather_qkv_bias<<<(L_ * 1536 + 255) / 256, 256, 0, stream>>>(bq, bk, bv, bqkv);
        pe_kernel<<<(S_ * D_) / 256, 256, 0, stream>>>(peT);
    }

    if (merged) {
        // ---- merged layout: one qkv GEMM + one attn dispatch per layer ----
        bf16* x16  = (bf16*)w; w += (size_t)NTALL * D_ * 2;
        bf16* ctxb = (bf16*)w; w += (size_t)NTALL * D_ * 2;   // also ffmid
        bf16* qkvh = (bf16*)w; w += QALL * 2 * 3;             // q|k|v, each NTALL rows
        bf16* x16h  = x16  + (size_t)NTMAIN * D_;
        bf16* ffmid = ctxb;
        bf16* sep16 = qkvh;                                   // temp before first qkv

        // sep projection first (sep16 dead before first qkv GEMM)
        {
            int n = B_ * NH_ * IMG_;
            cast_bf16<<<(n + 255) / 256, 256, 0, stream>>>(sep_img, sep16, n);
            gemm_mfma64<float><<<dim3(D_ / 128, (B_ * NH_) / 64), 256, 0, stream>>>(
                sep16, Wsept, bsep, sepb, B_ * NH_, D_, IMG_, 0, 0);
        }
        embed2_kernel<<<NTALL / 2, 256, 0, stream>>>(segment, prev_hist, emb, peT, x16);
        dim3 ga(D_ / 128, NTALL / 64);           // (4, 640)
        dim3 gq(1536 / 128, NTALL / 128);        // (12, 320)
        int attnBlocks = B_ * H_ * (S_ / 64) + B_ * NH_ * H_;  // 1024 + 1536
        for (int l = 0; l < L_; ++l) {
            size_t wl = (size_t)l * 1536 * D_;
            gemm_mfma<bf16><<<gq, 256, 0, stream>>>(
                x16, Wqkvt + wl, bqkv + l * 1536, qkvh, NTALL, 1536, D_, -2, 0, 0, 2);
            fused_attn2<<<attnBlocks, 256, 0, stream>>>(qkvh, ctxb, lens);
            gemm_mfma64<bf16><<<ga, 256, 0, stream>>>(
                ctxb, Wot + (size_t)l * D_ * D_, bo + l * D_, x16,
                NTALL, D_, D_, 0, 1);  // += resid
            ln_kernel<<<NTALL / 4, 256, 0, stream>>>(x16, ln1g + l * D_, ln1b + l * D_);
            gemm_mfma64<bf16><<<ga, 256, 0, stream>>>(
                x16, W1t + (size_t)l * D_ * FF_, b1 + l * FF_, ffmid,
                NTALL, FF_, D_, 1, 0);
            gemm_mfma64<bf16><<<ga, 256, 0, stream>>>(
                ffmid, W2t + (size_t)l * FF_ * D_, b2 + l * D_, x16,
                NTALL, D_, FF_, 0, 1); // += resid
            ln_kernel<<<NTALL / 4, 256, 0, stream>>>(x16, ln2g + l * D_, ln2b + l * D_);
        }
        copy_last_main<<<(B_ * D_) / 256, 256, 0, stream>>>(x16, bh);
        final_kernel<<<B_ * NH_, 256, 0, stream>>>(sepb, x16h, lens, bh, normalize, out);
    } else if (combined) {
        // ---- combined layout: shared qkv chunk, 2 qkv GEMMs/layer ----
        bf16* x16  = (bf16*)w; w += (size_t)NTALL * D_ * 2;
        bf16* ctxb = (bf16*)w; w += (size_t)NTALL * D_ * 2;   // also ffmid
        bf16* qh   = (bf16*)w; w += QCHUNK * 2;               // also sep16 temp
        bf16* kh   = (bf16*)w; w += QCHUNK * 2;
        bf16* vh   = (bf16*)w; w += QCHUNK * 2;
        bf16* x16h  = x16  + (size_t)NTMAIN * D_;
        bf16* ctxh  = ctxb + (size_t)NTMAIN * D_;
        bf16* ffmid = ctxb;
        bf16* sep16 = qh;

        {
            int n = B_ * NH_ * IMG_;
            cast_bf16<<<(n + 255) / 256, 256, 0, stream>>>(sep_img, sep16, n);
            gemm_mfma64<float><<<dim3(D_ / 128, (B_ * NH_) / 64), 256, 0, stream>>>(
                sep16, Wsept, bsep, sepb, B_ * NH_, D_, IMG_, 0, 0);
        }
        embed2_kernel<<<NTALL / 2, 256, 0, stream>>>(segment, prev_hist, emb, peT, x16);
        dim3 ga(D_ / 128, NTALL / 64);           // (4, 640)
        for (int l = 0; l < L_; ++l) {
            size_t wl = (size_t)l * 1536 * D_;
            gemm_mfma<bf16><<<dim3(12, NTMAIN / 128), 256, 0, stream>>>(
                x16, Wqkvt + wl, bqkv + l * 1536, qh, NTMAIN, 1536, D_, 8, 0, 0, 2);
            fused_attn<<<B_ * H_ * (S_ / 64), 256, 0, stream>>>(
                qh, kh, vh, ctxb, nullptr, S_, S_ / 64);
            gemm_mfma<bf16><<<dim3(12, NTHIST / 128), 256, 0, stream>>>(
                x16h, Wqkvt + wl, bqkv + l * 1536, qh, NTHIST, 1536, D_, 6, 0, 0, 2);
            fused_attn<<<B_ * NH_ * H_ * (T_ / 64), 256, 0, stream>>>(
                qh, kh, vh, ctxh, lens, T_, T_ / 64);
            gemm_mfma64<bf16><<<ga, 256, 0, stream>>>(
                ctxb, Wot + (size_t)l * D_ * D_, bo + l * D_, x16,
                NTALL, D_, D_, 0, 1);
            ln_kernel<<<NTALL / 4, 256, 0, stream>>>(x16, ln1g + l * D_, ln1b + l * D_);
            gemm_mfma64<bf16><<<ga, 256, 0, stream>>>(
                x16, W1t + (size_t)l * D_ * FF_, b1 + l * FF_, ffmid,
                NTALL, FF_, D_, 1, 0);
            gemm_mfma64<bf16><<<ga, 256, 0, stream>>>(
                ffmid, W2t + (size_t)l * FF_ * D_, b2 + l * D_, x16,
                NTALL, D_, FF_, 0, 1);
            ln_kernel<<<NTALL / 4, 256, 0, stream>>>(x16, ln2g + l * D_, ln2b + l * D_);
        }
        copy_last_main<<<(B_ * D_) / 256, 256, 0, stream>>>(x16, bh);
        final_kernel<<<B_ * NH_, 256, 0, stream>>>(sepb, x16h, lens, bh, normalize, out);
    } else {
        // ---- fallback: split layout/behavior ----
        bf16* x16  = (bf16*)w; w += QCHUNK * 2;
        bf16* ctxb = (bf16*)w; w += QCHUNK * 2;
        bf16* qh   = (bf16*)w; w += QCHUNK * 2;
        bf16* kh   = (bf16*)w; w += QCHUNK * 2;
        bf16* vh   = (bf16*)w; w += QCHUNK * 2;
        bf16* sep16 = (bf16*)w; w += (size_t)B_ * NH_ * IMG_ * 2;
        bf16* ffmid = qh;

        {
            int n = B_ * NH_ * IMG_;
            cast_bf16<<<(n + 255) / 256, 256, 0, stream>>>(sep_img, sep16, n);
        }
        auto run_encoder = [&](int M, int Tt, int lt, const int* lens_p) {
            int NT = M * Tt;
            dim3 gg(D_ / 128, NT / 64);
            dim3 gq(1536 / 128, NT / 128);
            int nqt = Tt / 64;
            for (int l = 0; l < L_; ++l) {
                gemm_mfma<bf16><<<gq, 256, 0, stream>>>(
                    x16, Wqkvt + (size_t)l * 1536 * D_, bqkv + l * 1536, qh,
                    NT, 1536, D_, lt, 0, 0, 2);
                fused_attn<<<M * H_ * nqt, 256, 0, stream>>>(
                    qh, kh, vh, ctxb, lens_p, Tt, nqt);
                gemm_mfma64<bf16><<<gg, 256, 0, stream>>>(
                    ctxb, Wot + (size_t)l * D_ * D_, bo + l * D_, x16,
                    NT, D_, D_, 0, 1);
                ln_kernel<<<NT / 4, 256, 0, stream>>>(x16, ln1g + l * D_, ln1b + l * D_);
                gemm_mfma64<bf16><<<gg, 256, 0, stream>>>(
                    x16, W1t + (size_t)l * D_ * FF_, b1 + l * FF_, ffmid,
                    NT, FF_, D_, 1, 0);
                gemm_mfma64<bf16><<<gg, 256, 0, stream>>>(
                    ffmid, W2t + (size_t)l * FF_ * D_, b2 + l * D_, x16,
                    NT, D_, FF_, 0, 1);
                ln_kernel<<<NT / 4, 256, 0, stream>>>(x16, ln2g + l * D_, ln2b + l * D_);
            }
        };
        embed_kernel<<<(NTMAIN * D_ / 4) / 256, 256, 0, stream>>>(
            segment, emb, peT, x16, S_, NTMAIN * D_ / 4);
        run_encoder(B_, S_, 8, nullptr);
        copy_last_main<<<(B_ * D_) / 256, 256, 0, stream>>>(x16, bh);
        gemm_mfma64<float><<<dim3(D_ / 128, (B_ * NH_) / 64), 256, 0, stream>>>(
            sep16, Wsept, bsep, sepb, B_ * NH_, D_, IMG_, 0, 0);
        embed_kernel<<<(NTHIST * D_ / 4) / 256, 256, 0, stream>>>(
            prev_hist, emb, peT, x16, T_, NTHIST * D_ / 4);
        run_encoder(B_ * NH_, T_, 6, lens);
        final_kernel<<<B_ * NH_, 256, 0, stream>>>(sepb, x16, lens, bh, normalize, out);
    }
}